// Round 9
// baseline (565.894 us; speedup 1.0000x reference)
//
#include <hip/hip_runtime.h>
#include <hip/hip_bf16.h>
#include <math.h>

#define B_   32
#define NA   512
#define NP   1024
#define HID  256
#define NH   8
#define DH   32
#define PF   1024

typedef short bf16x8 __attribute__((ext_vector_type(8)));
typedef float f32x4  __attribute__((ext_vector_type(4)));
typedef float f32x16 __attribute__((ext_vector_type(16)));
typedef unsigned u32x4 __attribute__((ext_vector_type(4)));

#define ZERO16 {0.f,0.f,0.f,0.f,0.f,0.f,0.f,0.f,0.f,0.f,0.f,0.f,0.f,0.f,0.f,0.f}

static __device__ inline unsigned short f2bf(float f) {
    __hip_bfloat16 h = __float2bfloat16(f);   // RNE; pairs fuse to v_cvt_pk_bf16_f32
    unsigned short u;
    __builtin_memcpy(&u, &h, 2);
    return u;
}
static __device__ inline unsigned cvtpk(float lo, float hi) {
    return (unsigned)f2bf(lo) | ((unsigned)f2bf(hi) << 16);
}
static __device__ inline bf16x8 pack8(float4 a, float4 b) {
    bf16x8 r;
    r[0] = (short)f2bf(a.x); r[1] = (short)f2bf(a.y);
    r[2] = (short)f2bf(a.z); r[3] = (short)f2bf(a.w);
    r[4] = (short)f2bf(b.x); r[5] = (short)f2bf(b.y);
    r[6] = (short)f2bf(b.z); r[7] = (short)f2bf(b.w);
    return r;
}

// ---------------- feature transform: x = trg @ ft_w.T + ft_b (fp32 + bf16) --
__global__ __launch_bounds__(256) void ft_kernel(const float* __restrict__ trg,
    const float* __restrict__ w, const float* __restrict__ b,
    float* __restrict__ out, unsigned short* __restrict__ outb)
{
    __shared__ float Ws[256][35];
    int tid = threadIdx.x;
    for (int k = 0; k < 34; ++k) Ws[tid][k] = w[tid*34 + k];
    float bias = b[tid];
    __syncthreads();
    int m0 = blockIdx.x * 32;
    for (int r = 0; r < 32; ++r) {
        int m = m0 + r;
        const float* tr = trg + (size_t)m*34;
        float acc = bias;
        #pragma unroll
        for (int k = 0; k < 34; ++k) acc += tr[k] * Ws[tid][k];
        out [(size_t)m*HID + tid] = acc;
        outb[(size_t)m*HID + tid] = f2bf(acc);
    }
}

// ---------------- fp32 -> bf16 bulk convert ---------------------------------
__global__ __launch_bounds__(256) void cvt_bf16(const float* __restrict__ in,
    unsigned short* __restrict__ outb, int n8)
{
    int i = blockIdx.x*256 + threadIdx.x;
    int stride = gridDim.x*256;
    for (; i < n8; i += stride) {
        float4 a = *(const float4*)(in + (size_t)i*8);
        float4 b = *(const float4*)(in + (size_t)i*8 + 4);
        *(bf16x8*)(outb + (size_t)i*8) = pack8(a, b);
    }
}

// ---------------- weight pre-convert (10 tensors, one launch) ---------------
__global__ __launch_bounds__(256) void cvt_w(
    const float* __restrict__ s0, const float* __restrict__ s1,
    const float* __restrict__ s2, const float* __restrict__ s3,
    const float* __restrict__ s4, const float* __restrict__ s5,
    const float* __restrict__ s6, const float* __restrict__ s7,
    const float* __restrict__ s8, const float* __restrict__ s9,
    unsigned short* __restrict__ dst)
{
    const int z = blockIdx.z;
    const float* src;
    switch (z) {
        case 0: src = s0; break; case 1: src = s1; break;
        case 2: src = s2; break; case 3: src = s3; break;
        case 4: src = s4; break; case 5: src = s5; break;
        case 6: src = s6; break; case 7: src = s7; break;
        case 8: src = s8; break; default: src = s9; break;
    }
    const int n8 = (z < 8) ? 16384 : 65536;
    const size_t off = (z < 8) ? (size_t)z*131072 : (1048576u + (size_t)(z-8)*524288);
    unsigned short* o = dst + off;
    int i = blockIdx.x*256 + threadIdx.x;
    const int stride = gridDim.x*256;
    for (; i < n8; i += stride) {
        float4 a = *(const float4*)(src + (size_t)i*8);
        float4 b = *(const float4*)(src + (size_t)i*8 + 4);
        *(bf16x8*)(o + (size_t)i*8) = pack8(a, b);
    }
}

// ---------------- bf16 MFMA GEMM core v2: 128x128 tile ----------------------
// C[M,N] = A[M,K] @ W[N,K]^T + bias. A, W bf16.
// Fragment-major LDS for both operands: unit (fi*64+lane)*8 holds the 16B
// MFMA fragment slice; every ds_read/ds_write is wave-contiguous (0 conflict).
// mode: 0 fp32 out; 1 bf16 out; 3 bf16 relu out;
// 4 bf16 K-fragment-major; 5 bf16 V-fragment-major (see attention).
static __device__ inline void gemm_core(const unsigned short* __restrict__ Ab,
    const unsigned short* __restrict__ Wb, const float* __restrict__ bias,
    void* __restrict__ Cv, int M, int N, int K, int mode, int L, float oscale,
    int bx, int by)
{
    __shared__ __attribute__((aligned(16))) unsigned short Af[16*64*8]; // 16KB
    __shared__ __attribute__((aligned(16))) unsigned short Wf[16*64*8]; // 16KB
    const int tid = threadIdx.x;
    const int wave = tid >> 6, lane = tid & 63, lq = lane & 15, g = lane >> 4;
    const int wr = wave >> 1, wc = wave & 1;
    const int m0 = by * 128, n0 = bx * 128;

    const int ar = tid >> 1, ac = (tid & 1) * 32;   // stage: 2 thr/row, 32 elems
    const int fbase = (ar >> 4)*2 + (tid & 1);      // frag row block + k-half
    const int lslot = ar & 15;

    f32x4 acc[4][4] = {};
    bf16x8 sa[4], sw[4];

    auto LOAD = [&](int kt) {
        const int k0 = kt * 64;
        const unsigned short* Ap = Ab + (size_t)(m0 + ar)*K + k0 + ac;
        #pragma unroll
        for (int i = 0; i < 4; ++i) sa[i] = *(const bf16x8*)(Ap + i*8);
        const unsigned short* Wp = Wb + (size_t)(n0 + ar)*K + k0 + ac;
        #pragma unroll
        for (int i = 0; i < 4; ++i) sw[i] = *(const bf16x8*)(Wp + i*8);
    };
    auto STORE = [&]() {
        #pragma unroll
        for (int i = 0; i < 4; ++i)
            *(bf16x8*)&Af[((size_t)fbase*64 + lslot + 16*i)*8] = sa[i];
        #pragma unroll
        for (int i = 0; i < 4; ++i)
            *(bf16x8*)&Wf[((size_t)fbase*64 + lslot + 16*i)*8] = sw[i];
    };

    const int nk = K / 64;
    LOAD(0);
    for (int kt = 0; kt < nk; ++kt) {
        __syncthreads();
        STORE();
        __syncthreads();
        if (kt + 1 < nk) LOAD(kt + 1);
        #pragma unroll
        for (int ks = 0; ks < 2; ++ks) {
            bf16x8 bfr[4];
            #pragma unroll
            for (int j = 0; j < 4; ++j)
                bfr[j] = *(const bf16x8*)&Wf[((size_t)(((wc*4+j)*2+ks)*64) + lane)*8];
            #pragma unroll
            for (int i = 0; i < 4; ++i) {
                bf16x8 af = *(const bf16x8*)&Af[((size_t)(((wr*4+i)*2+ks)*64) + lane)*8];
                #pragma unroll
                for (int j = 0; j < 4; ++j)
                    acc[i][j] = __builtin_amdgcn_mfma_f32_16x16x32_bf16(af, bfr[j], acc[i][j], 0, 0, 0);
            }
        }
    }

    float bb[4];
    #pragma unroll
    for (int j = 0; j < 4; ++j) bb[j] = bias[n0 + wc*64 + j*16 + lq];

    #pragma unroll
    for (int i = 0; i < 4; ++i) {
        const int mb = m0 + wr*64 + i*16 + 4*g;
        #pragma unroll
        for (int j = 0; j < 4; ++j) {
            const int n = n0 + wc*64 + j*16 + lq;
            f32x4 v = acc[i][j];
            #pragma unroll
            for (int r = 0; r < 4; ++r) v[r] = (v[r] + bb[j]) * oscale;
            if (mode == 0) {
                float* Cf = (float*)Cv;
                #pragma unroll
                for (int r = 0; r < 4; ++r) Cf[(size_t)(mb + r)*N + n] = v[r];
            } else if (mode == 1) {
                unsigned short* Cb = (unsigned short*)Cv;
                #pragma unroll
                for (int r = 0; r < 4; ++r) Cb[(size_t)(mb + r)*N + n] = f2bf(v[r]);
            } else if (mode == 3) {
                unsigned short* Cb = (unsigned short*)Cv;
                #pragma unroll
                for (int r = 0; r < 4; ++r) Cb[(size_t)(mb + r)*N + n] = f2bf(fmaxf(v[r], 0.f));
            } else if (mode == 4) {
                unsigned short* Cb = (unsigned short*)Cv;
                const int bI = mb / L, kk = mb % L;
                const int hh = n >> 5, d = n & 31;
                const int t2 = kk >> 5, dc = d >> 4, hi2 = (d >> 3) & 1;
                unsigned short* base = Cb
                    + ((size_t)(((bI*NH + hh)*(L >> 5) + t2)*2 + dc))*512
                    + ((kk & 31) + 32*hi2)*8 + (d & 7);
                base[0]  = f2bf(v[0]); base[8]  = f2bf(v[1]);
                base[16] = f2bf(v[2]); base[24] = f2bf(v[3]);
            } else {
                // mode 5: V fragment-major (contiguous ushort4)
                unsigned short* Cb = (unsigned short*)Cv;
                const int bI = mb / L, kk = mb % L;
                const int hh = n >> 5, d = n & 31;
                const int t = kk >> 6, oct = (kk >> 3) & 7;
                const int c = oct >> 1, hiV = oct & 1;
                ushort4 pk;
                pk.x = f2bf(v[0]); pk.y = f2bf(v[1]); pk.z = f2bf(v[2]); pk.w = f2bf(v[3]);
                *(ushort4*)(Cb
                    + ((size_t)(((bI*NH + hh)*(L >> 6) + t)*4 + c))*512
                    + (d + 32*hiV)*8 + (kk & 7)) = pk;
            }
        }
    }
}

// XCD-chunked swizzle over a 2D (nx,ny) grid slice; requires (nx*ny)%8==0.
static __device__ inline void xcd_swz(int d, int nx, int nxy, int& bx, int& by)
{
    const int w = (d & 7) * (nxy >> 3) + (d >> 3);
    bx = w % nx; by = w / nx;
}

__global__ __launch_bounds__(256) void gemm_mfma(const unsigned short* __restrict__ A,
    const unsigned short* __restrict__ W, const float* __restrict__ bias,
    void* __restrict__ C, int M, int N, int K, int mode, int L)
{
    int bx, by;
    xcd_swz(blockIdx.y*gridDim.x + blockIdx.x, gridDim.x, gridDim.x*gridDim.y, bx, by);
    gemm_core(A, W, bias, C, M, N, K, mode, L, 1.f, bx, by);
}

// fused Q/K/V projections: blockIdx.z selects which. Q pre-scaled by
// log2(e)/sqrt(32); K/V written fragment-major for register-direct attention.
__global__ __launch_bounds__(256) void qkv_mfma(const unsigned short* __restrict__ Aq,
    const unsigned short* __restrict__ Akv,
    const unsigned short* __restrict__ Wq, const float* __restrict__ bq,
    const unsigned short* __restrict__ Wk, const float* __restrict__ bk,
    const unsigned short* __restrict__ Wv, const float* __restrict__ bv,
    void* __restrict__ qo, void* __restrict__ ko, void* __restrict__ vo,
    int Mq, int Mkv, int L)
{
    const int z = blockIdx.z;
    const unsigned short* A = (z == 0) ? Aq : Akv;
    const unsigned short* W = (z == 0) ? Wq : ((z == 1) ? Wk : Wv);
    const float* bb = (z == 0) ? bq : ((z == 1) ? bk : bv);
    void* C = (z == 0) ? qo : ((z == 1) ? ko : vo);
    const int M = (z == 0) ? Mq : Mkv;
    const int mode = (z == 0) ? 1 : ((z == 1) ? 4 : 5);
    const float sc = (z == 0) ? 0.25504082364238727f : 1.f;   // log2(e)/sqrt(32)
    int bx, by;
    xcd_swz(blockIdx.y*gridDim.x + blockIdx.x, gridDim.x, gridDim.x*gridDim.y, bx, by);
    if (by * 128 >= M) return;
    gemm_core(A, W, bb, C, M, HID, HID, mode, L, sc, bx, by);
}

// ---------------- fused MFMA attention v6 ------------------------------------
// Register-dataflow flash attention: 32x32x16 MFMA, max-free softmax (Q
// pre-scaled), in-register P via cvt_pk + permlane32_swap. K/V come from
// fragment-major global layouts (KF/VF) so every operand load is ONE
// wave-contiguous 1KB global_load_dwordx4. No LDS staging, no barriers.
__global__ __launch_bounds__(256) void attn_mfma(const unsigned short* __restrict__ Qb,
    const unsigned short* __restrict__ KF, const unsigned short* __restrict__ VF,
    unsigned short* __restrict__ O, int Lk)
{
    __shared__ float Ll[4][32];
    const int orig = blockIdx.x;
    const int sw = (orig & 7) * 128 + (orig >> 3);   // XCD-chunk swizzle (1024%8==0)
    const int qt = sw & 3;
    const int h  = (sw >> 2) & 7;
    const int b  = sw >> 5;
    const int tid = threadIdx.x, w = tid >> 6, lane = tid & 63;
    const int q32 = lane & 31, hi = lane >> 5;

    // Q fragments (B-operand): lane -> (q=q32, d = dc*16 + hi*8 ..+7)
    const unsigned short* qp = Qb + ((size_t)(b*NA + qt*128 + w*32 + q32))*HID + h*DH + hi*8;
    bf16x8 qf0 = *(const bf16x8*)qp;
    bf16x8 qf1 = *(const bf16x8*)(qp + 16);

    const unsigned short* Kf = KF + (size_t)((b*NH + h)*(Lk >> 5)*2)*512 + lane*8;
    const unsigned short* Vf = VF + (size_t)((b*NH + h)*(Lk >> 6)*4)*512 + lane*8;

    f32x16 o_acc = ZERO16;
    float lacc = 0.f;

    bf16x8 kfA[4], kfB[4], vfT[4];
    auto LOADK = [&](int t, bf16x8* kd) {
        #pragma unroll
        for (int f = 0; f < 4; ++f)
            kd[f] = *(const bf16x8*)(Kf + (size_t)(t*4 + f)*512);
    };
    auto STEP = [&](const bf16x8* kf, int t) {
        #pragma unroll
        for (int c = 0; c < 4; ++c)
            vfT[c] = *(const bf16x8*)(Vf + (size_t)(t*4 + c)*512);
        f32x16 st0 = ZERO16, st1 = ZERO16;
        st0 = __builtin_amdgcn_mfma_f32_32x32x16_bf16(kf[0], qf0, st0, 0, 0, 0);
        st0 = __builtin_amdgcn_mfma_f32_32x32x16_bf16(kf[1], qf1, st0, 0, 0, 0);
        st1 = __builtin_amdgcn_mfma_f32_32x32x16_bf16(kf[2], qf0, st1, 0, 0, 0);
        st1 = __builtin_amdgcn_mfma_f32_32x32x16_bf16(kf[3], qf1, st1, 0, 0, 0);
        bf16x8 pa[4];
        float lp = 0.f;
        #pragma unroll
        for (int c = 0; c < 4; ++c) {
            const f32x16& s = (c < 2) ? st0 : st1;
            const int rb = (c & 1) * 8;
            float p0 = __builtin_amdgcn_exp2f(s[rb+0]);
            float p1 = __builtin_amdgcn_exp2f(s[rb+1]);
            float p2 = __builtin_amdgcn_exp2f(s[rb+2]);
            float p3 = __builtin_amdgcn_exp2f(s[rb+3]);
            float p4 = __builtin_amdgcn_exp2f(s[rb+4]);
            float p5 = __builtin_amdgcn_exp2f(s[rb+5]);
            float p6 = __builtin_amdgcn_exp2f(s[rb+6]);
            float p7 = __builtin_amdgcn_exp2f(s[rb+7]);
            lp += (p0+p1) + (p2+p3) + (p4+p5) + (p6+p7);
            unsigned A1 = cvtpk(p0, p1), A2 = cvtpk(p2, p3);
            unsigned B1 = cvtpk(p4, p5), B2 = cvtpk(p6, p7);
            auto r1 = __builtin_amdgcn_permlane32_swap(A1, B1, false, false);
            auto r2 = __builtin_amdgcn_permlane32_swap(A2, B2, false, false);
            u32x4 pw; pw[0] = r1[0]; pw[1] = r2[0]; pw[2] = r1[1]; pw[3] = r2[1];
            __builtin_memcpy(&pa[c], &pw, 16);
        }
        lacc += lp;
        #pragma unroll
        for (int c = 0; c < 4; ++c)
            o_acc = __builtin_amdgcn_mfma_f32_32x32x16_bf16(pa[c], vfT[c], o_acc, 0, 0, 0);
    };

    const int nt = Lk >> 6;   // 8 or 16 (even)
    LOADK(0, kfA);
    for (int t = 0; t < nt; t += 2) {
        LOADK(t + 1, kfB);
        STEP(kfA, t);
        if (t + 2 < nt) LOADK(t + 2, kfA);
        STEP(kfB, t + 1);
    }

    float lt = lacc + __shfl_xor(lacc, 32);
    float linv = 1.f / lt;
    if (hi == 0) Ll[w][q32] = linv;
    f32x4 li[4];
    #pragma unroll
    for (int jg = 0; jg < 4; ++jg) li[jg] = *(const f32x4*)&Ll[w][jg*8 + hi*4];

    unsigned short* Op = O + ((size_t)(b*NA + qt*128 + w*32))*HID + h*DH + q32;
    #pragma unroll
    for (int jg = 0; jg < 4; ++jg) {
        #pragma unroll
        for (int r2 = 0; r2 < 4; ++r2) {
            const int q = jg*8 + hi*4 + r2;
            Op[(size_t)q*HID] = f2bf(o_acc[jg*4 + r2] * li[jg][r2]);
        }
    }
}

// ---------------- residual add + LayerNorm (wave per row, dual output) ------
__global__ __launch_bounds__(256) void add_ln(float* __restrict__ x,
    const float* __restrict__ t, const float* __restrict__ g,
    const float* __restrict__ bt, unsigned short* __restrict__ xb)
{
    const int row = blockIdx.x*4 + (threadIdx.x >> 6);
    const int lane = threadIdx.x & 63;
    const size_t base = (size_t)row*HID + lane*4;
    float4 v = *(const float4*)(x + base);
    float4 tv = *(const float4*)(t + base);
    v.x += tv.x; v.y += tv.y; v.z += tv.z; v.w += tv.w;
    float s = v.x + v.y + v.z + v.w;
    #pragma unroll
    for (int o = 32; o > 0; o >>= 1) s += __shfl_xor(s, o);
    float mean = s * (1.f/256.f);
    float4 d = {v.x - mean, v.y - mean, v.z - mean, v.w - mean};
    float q2 = d.x*d.x + d.y*d.y + d.z*d.z + d.w*d.w;
    #pragma unroll
    for (int o = 32; o > 0; o >>= 1) q2 += __shfl_xor(q2, o);
    float rs = rsqrtf(q2*(1.f/256.f) + 1e-5f);
    float4 gv = *(const float4*)(g + lane*4);
    float4 bv = *(const float4*)(bt + lane*4);
    float4 ov;
    ov.x = d.x*rs*gv.x + bv.x; ov.y = d.y*rs*gv.y + bv.y;
    ov.z = d.z*rs*gv.z + bv.z; ov.w = d.w*rs*gv.w + bv.w;
    *(float4*)(x + base) = ov;
    ushort4 pk;
    pk.x = f2bf(ov.x); pk.y = f2bf(ov.y); pk.z = f2bf(ov.z); pk.w = f2bf(ov.w);
    *(ushort4*)(xb + base) = pk;
}

// ---------------- pooling: row norms (wave per row) -------------------------
__global__ __launch_bounds__(256) void norms_k(const float* __restrict__ x,
    float* __restrict__ nw)
{
    const int row = blockIdx.x*4 + (threadIdx.x >> 6);
    const int lane = threadIdx.x & 63;
    float4 v = *(const float4*)(x + (size_t)row*HID + lane*4);
    float s = v.x*v.x + v.y*v.y + v.z*v.z + v.w*v.w;
    #pragma unroll
    for (int o = 32; o > 0; o >>= 1) s += __shfl_xor(s, o);
    if (lane == 0) nw[row] = sqrtf(s);
}

// ---------------- pooling: softmax-weighted sum over rows -------------------
__global__ __launch_bounds__(256) void pooled_k(const float* __restrict__ x,
    const float* __restrict__ nw, float* __restrict__ pooled)
{
    __shared__ float sw[NA];
    __shared__ float red[256];
    __shared__ float part[8][33];
    const int b = blockIdx.x, hc = blockIdx.y;
    const int tid = threadIdx.x;
    const float* nb = nw + (size_t)b*NA;
    float v0 = nb[tid], v1 = nb[tid + 256];
    red[tid] = fmaxf(v0, v1); __syncthreads();
    for (int s = 128; s > 0; s >>= 1) { if (tid < s) red[tid] = fmaxf(red[tid], red[tid+s]); __syncthreads(); }
    float mx = red[0]; __syncthreads();
    float e0 = __expf(v0 - mx), e1 = __expf(v1 - mx);
    sw[tid] = e0; sw[tid + 256] = e1;
    red[tid] = e0 + e1; __syncthreads();
    for (int s = 128; s > 0; s >>= 1) { if (tid < s) red[tid] += red[tid+s]; __syncthreads(); }
    float inv = 1.f / red[0];
    __syncthreads();
    const int ng = tid >> 5, col = tid & 31;
    const float* xp = x + (size_t)b*NA*HID + hc*32 + col;
    float acc = 0.f;
    for (int n = ng; n < NA; n += 8)
        acc += sw[n] * xp[(size_t)n*HID];
    part[ng][col] = acc;
    __syncthreads();
    if (tid < 32) {
        float s = 0.f;
        #pragma unroll
        for (int i = 0; i < 8; ++i) s += part[i][tid];
        pooled[(size_t)b*HID + hc*32 + tid] = s * inv;
    }
}

// ---------------- FC head ---------------------------------------------------
__global__ __launch_bounds__(256) void head_k(const float* __restrict__ pooled,
    const float* __restrict__ fc1w, const float* __restrict__ fc1b,
    const float* __restrict__ fc2w, const float* __restrict__ fc2b,
    float* __restrict__ out)
{
    __shared__ float p[HID];
    __shared__ float a1[HID];
    const int b = blockIdx.x, tid = threadIdx.x;
    p[tid] = pooled[(size_t)b*HID + tid];
    __syncthreads();
    float s1 = fc1b[tid];
    const float* w1 = fc1w + (size_t)tid*HID;
    for (int k2 = 0; k2 < HID; k2 += 4) {
        float4 w = *(const float4*)(w1 + k2);
        s1 += p[k2]*w.x + p[k2+1]*w.y + p[k2+2]*w.z + p[k2+3]*w.w;
    }
    a1[tid] = fmaxf(s1, 0.f);
    __syncthreads();
    if (tid < 2) {
        float s2 = fc2b[tid];
        const float* w2 = fc2w + (size_t)tid*HID;
        for (int k2 = 0; k2 < HID; ++k2) s2 += a1[k2] * w2[k2];
        out[b*2 + tid] = s2;
    }
}

// ---------------- launch ----------------------------------------------------
extern "C" void kernel_launch(void* const* d_in, const int* in_sizes, int n_in,
                              void* d_out, int out_size, void* d_ws, size_t ws_size,
                              hipStream_t stream)
{
    const float* trg  = (const float*)d_in[0];
    const float* src  = (const float*)d_in[1];
    const float* ft_w = (const float*)d_in[2];
    const float* ft_b = (const float*)d_in[3];
    const float* ln_g = (const float*)d_in[4];
    const float* ln_b = (const float*)d_in[5];
    const float* sa_wq = (const float*)d_in[6];  const float* sa_bq = (const float*)d_in[7];
    const float* sa_wk = (const float*)d_in[8];  const float* sa_bk = (const float*)d_in[9];
    const float* sa_wv = (const float*)d_in[10]; const float* sa_bv = (const float*)d_in[11];
    const float* sa_wf = (const float*)d_in[12]; const float* sa_bf = (const float*)d_in[13];
    const float* ea_wq = (const float*)d_in[14]; const float* ea_bq = (const float*)d_in[15];
    const float* ea_wk = (const float*)d_in[16]; const float* ea_bk = (const float*)d_in[17];
    const float* ea_wv = (const float*)d_in[18]; const float* ea_bv = (const float*)d_in[19];
    const float* ea_wf = (const float*)d_in[20]; const float* ea_bf = (const float*)d_in[21];
    const float* pf_w1 = (const float*)d_in[22]; const float* pf_b1 = (const float*)d_in[23];
    const float* pf_w2 = (const float*)d_in[24]; const float* pf_b2 = (const float*)d_in[25];
    const float* fc1w  = (const float*)d_in[26]; const float* fc1b  = (const float*)d_in[27];
    const float* fc2w  = (const float*)d_in[28]; const float* fc2b  = (const float*)d_in[29];
    float* out = (float*)d_out;

    const size_t NTOK = (size_t)B_*NA;    // 16384
    const size_t NSRC = (size_t)B_*NP;    // 32768
    float* ws = (float*)d_ws;
    float* x  = ws;                        // [NTOK,HID] fp32 master
    float* u  = x + NTOK*HID;              // [NTOK,HID] fp32 (proj/ffn2 out)
    float* nw = u + NTOK*HID;              // [NTOK] row norms
    float* pooled = nw + NTOK;             // [B_,HID]
    unsigned short* xb   = (unsigned short*)(pooled + B_*HID); // [NTOK,HID] bf16 shadow
    unsigned short* tb   = xb + NTOK*HID;                      // [NTOK,HID] bf16 attn-out
    unsigned short* srcb = tb + NTOK*HID;                      // [NSRC,HID] bf16
    unsigned short* qb   = srcb + NSRC*HID;                    // [NTOK,HID] bf16
    unsigned short* kb   = qb + NTOK*HID;                      // KF fragment-major bf16
    unsigned short* vTb  = kb + NSRC*HID;                      // VF fragment-major bf16
    unsigned short* wb   = vTb + NSRC*HID;                     // 2097152 bf16 weights
    unsigned short* hb   = qb;             // [NTOK,PF] bf16 aliases qb..vTb

    // pre-converted weight pointers
    unsigned short* saq_b = wb;
    unsigned short* sak_b = wb +  131072;
    unsigned short* sav_b = wb +  262144;
    unsigned short* saf_b = wb +  393216;
    unsigned short* eaq_b = wb +  524288;
    unsigned short* eak_b = wb +  655360;
    unsigned short* eav_b = wb +  786432;
    unsigned short* eaf_b = wb +  917504;
    unsigned short* pw1_b = wb + 1048576;
    unsigned short* pw2_b = wb + 1572864;

    const int M = (int)NTOK;
    dim3 blk(256);

    cvt_w<<<dim3(64, 1, 10), blk, 0, stream>>>(sa_wq, sa_wk, sa_wv, sa_wf,
        ea_wq, ea_wk, ea_wv, ea_wf, pf_w1, pf_w2, wb);
    ft_kernel<<<M/32, blk, 0, stream>>>(trg, ft_w, ft_b, x, xb);
    cvt_bf16<<<1024, blk, 0, stream>>>(src, srcb, (int)(NSRC*HID/8));

    for (int l = 0; l < 2; ++l) {
        const size_t wo = (size_t)l*HID*HID, bo = (size_t)l*HID;
        // ---- self attention ----
        qkv_mfma<<<dim3(HID/128, M/128, 3), blk, 0, stream>>>(xb, xb,
            saq_b+wo, sa_bq+bo, sak_b+wo, sa_bk+bo, sav_b+wo, sa_bv+bo,
            qb, kb, vTb, M, M, NA);
        attn_mfma<<<dim3(1024), blk, 0, stream>>>(qb, kb, vTb, tb, NA);
        gemm_mfma<<<dim3(HID/128, M/128), blk, 0, stream>>>(tb, saf_b+wo, sa_bf+bo, u, M, HID, HID, 0, 0);
        add_ln<<<M/4, blk, 0, stream>>>(x, u, ln_g+bo, ln_b+bo, xb);
        // ---- cross attention ----
        qkv_mfma<<<dim3(HID/128, (int)NSRC/128, 3), blk, 0, stream>>>(xb, srcb,
            eaq_b+wo, ea_bq+bo, eak_b+wo, ea_bk+bo, eav_b+wo, ea_bv+bo,
            qb, kb, vTb, M, (int)NSRC, NP);
        attn_mfma<<<dim3(1024), blk, 0, stream>>>(qb, kb, vTb, tb, NP);
        gemm_mfma<<<dim3(HID/128, M/128), blk, 0, stream>>>(tb, eaf_b+wo, ea_bf+bo, u, M, HID, HID, 0, 0);
        add_ln<<<M/4, blk, 0, stream>>>(x, u, ln_g+bo, ln_b+bo, xb);
        // ---- feed-forward ----
        gemm_mfma<<<dim3(PF/128, M/128), blk, 0, stream>>>(xb, pw1_b+(size_t)l*PF*HID, pf_b1+(size_t)l*PF, hb, M, PF, HID, 3, 0);
        gemm_mfma<<<dim3(HID/128, M/128), blk, 0, stream>>>(hb, pw2_b+(size_t)l*HID*PF, pf_b2+bo, u, M, HID, PF, 0, 0);
        add_ln<<<M/4, blk, 0, stream>>>(x, u, ln_g+bo, ln_b+bo, xb);
    }

    norms_k<<<M/4, blk, 0, stream>>>(x, nw);
    pooled_k<<<dim3(B_, 8), blk, 0, stream>>>(x, nw, pooled);
    head_k<<<B_, blk, 0, stream>>>(pooled, fc1w, fc1b, fc2w, fc2b, out);
}

// Round 10
// 444.304 us; speedup vs baseline: 1.2737x; 1.2737x over previous
//
#include <hip/hip_runtime.h>
#include <hip/hip_bf16.h>
#include <math.h>

#define B_   32
#define NA   512
#define NP   1024
#define HID  256
#define NH   8
#define DH   32
#define PF   1024

typedef short bf16x8 __attribute__((ext_vector_type(8)));
typedef float f32x4  __attribute__((ext_vector_type(4)));
typedef float f32x16 __attribute__((ext_vector_type(16)));
typedef unsigned u32x4 __attribute__((ext_vector_type(4)));

#define ZERO16 {0.f,0.f,0.f,0.f,0.f,0.f,0.f,0.f,0.f,0.f,0.f,0.f,0.f,0.f,0.f,0.f}

static __device__ inline unsigned short f2bf(float f) {
    __hip_bfloat16 h = __float2bfloat16(f);   // RNE; pairs fuse to v_cvt_pk_bf16_f32
    unsigned short u;
    __builtin_memcpy(&u, &h, 2);
    return u;
}
static __device__ inline float bf2f(unsigned short u) {
    unsigned x = ((unsigned)u) << 16;
    return __uint_as_float(x);
}
static __device__ inline unsigned cvtpk(float lo, float hi) {
    return (unsigned)f2bf(lo) | ((unsigned)f2bf(hi) << 16);
}
static __device__ inline bf16x8 pack8(float4 a, float4 b) {
    bf16x8 r;
    r[0] = (short)f2bf(a.x); r[1] = (short)f2bf(a.y);
    r[2] = (short)f2bf(a.z); r[3] = (short)f2bf(a.w);
    r[4] = (short)f2bf(b.x); r[5] = (short)f2bf(b.y);
    r[6] = (short)f2bf(b.z); r[7] = (short)f2bf(b.w);
    return r;
}

// ---------------- feature transform: x = trg @ ft_w.T + ft_b (fp32 + bf16) --
__global__ __launch_bounds__(256) void ft_kernel(const float* __restrict__ trg,
    const float* __restrict__ w, const float* __restrict__ b,
    float* __restrict__ out, unsigned short* __restrict__ outb)
{
    __shared__ float Ws[256][35];
    int tid = threadIdx.x;
    for (int k = 0; k < 34; ++k) Ws[tid][k] = w[tid*34 + k];
    float bias = b[tid];
    __syncthreads();
    int m0 = blockIdx.x * 32;
    for (int r = 0; r < 32; ++r) {
        int m = m0 + r;
        const float* tr = trg + (size_t)m*34;
        float acc = bias;
        #pragma unroll
        for (int k = 0; k < 34; ++k) acc += tr[k] * Ws[tid][k];
        out [(size_t)m*HID + tid] = acc;
        outb[(size_t)m*HID + tid] = f2bf(acc);
    }
}

// ---------------- fp32 -> bf16 bulk convert ---------------------------------
__global__ __launch_bounds__(256) void cvt_bf16(const float* __restrict__ in,
    unsigned short* __restrict__ outb, int n8)
{
    int i = blockIdx.x*256 + threadIdx.x;
    int stride = gridDim.x*256;
    for (; i < n8; i += stride) {
        float4 a = *(const float4*)(in + (size_t)i*8);
        float4 b = *(const float4*)(in + (size_t)i*8 + 4);
        *(bf16x8*)(outb + (size_t)i*8) = pack8(a, b);
    }
}

// ---------------- weight pre-convert (10 tensors, one launch) ---------------
__global__ __launch_bounds__(256) void cvt_w(
    const float* __restrict__ s0, const float* __restrict__ s1,
    const float* __restrict__ s2, const float* __restrict__ s3,
    const float* __restrict__ s4, const float* __restrict__ s5,
    const float* __restrict__ s6, const float* __restrict__ s7,
    const float* __restrict__ s8, const float* __restrict__ s9,
    unsigned short* __restrict__ dst)
{
    const int z = blockIdx.z;
    const float* src;
    switch (z) {
        case 0: src = s0; break; case 1: src = s1; break;
        case 2: src = s2; break; case 3: src = s3; break;
        case 4: src = s4; break; case 5: src = s5; break;
        case 6: src = s6; break; case 7: src = s7; break;
        case 8: src = s8; break; default: src = s9; break;
    }
    const int n8 = (z < 8) ? 16384 : 65536;
    const size_t off = (z < 8) ? (size_t)z*131072 : (1048576u + (size_t)(z-8)*524288);
    unsigned short* o = dst + off;
    int i = blockIdx.x*256 + threadIdx.x;
    const int stride = gridDim.x*256;
    for (; i < n8; i += stride) {
        float4 a = *(const float4*)(src + (size_t)i*8);
        float4 b = *(const float4*)(src + (size_t)i*8 + 4);
        *(bf16x8*)(o + (size_t)i*8) = pack8(a, b);
    }
}

// ---------------- bf16 MFMA GEMM core (R8-proven 128x64 tile) ---------------
// C[M,N] = A[M,K] @ W[N,K]^T + bias. A, W bf16.
// mode: 0 fp32 out; 1 bf16 out; 3 bf16 relu out;
// 4 bf16 K-fragment-major; 5 bf16 V-fragment-major (see attention).
static __device__ inline void gemm_core(const unsigned short* __restrict__ Ab,
    const unsigned short* __restrict__ Wb, const float* __restrict__ bias,
    void* __restrict__ Cv, int M, int N, int K, int mode, int L, float oscale,
    int bx, int by)
{
    __shared__ __attribute__((aligned(16))) unsigned short As[128][72]; // 144B rows
    __shared__ __attribute__((aligned(16))) unsigned short Bs[64][72];
    const int tid = threadIdx.x;
    const int wave = tid >> 6, lane = tid & 63, lq = lane & 15, g = lane >> 4;
    const int wr = wave >> 1, wc = wave & 1;
    const int m0 = by * 128, n0 = bx * 64;

    const int ar = tid >> 1, ac = (tid & 1) * 32;   // A stage: 2 thr/row, 32 elems
    const int br = tid >> 2, bc = (tid & 3) * 16;   // W stage: 4 thr/row, 16 elems

    f32x4 acc[4][2] = {};
    bf16x8 sa[4], sw[2];

    auto LOAD = [&](int kt) {
        const int k0 = kt * 64;
        const unsigned short* Ap = Ab + (size_t)(m0 + ar)*K + k0 + ac;
        #pragma unroll
        for (int i = 0; i < 4; ++i)
            sa[i] = *(const bf16x8*)(Ap + i*8);
        const unsigned short* Wp = Wb + (size_t)(n0 + br)*K + k0 + bc;
        #pragma unroll
        for (int i = 0; i < 2; ++i)
            sw[i] = *(const bf16x8*)(Wp + i*8);
    };
    auto STORE = [&]() {
        #pragma unroll
        for (int i = 0; i < 4; ++i) *(bf16x8*)&As[ar][ac + i*8] = sa[i];
        #pragma unroll
        for (int i = 0; i < 2; ++i) *(bf16x8*)&Bs[br][bc + i*8] = sw[i];
    };

    const int nk = K / 64;
    LOAD(0);
    for (int kt = 0; kt < nk; ++kt) {
        __syncthreads();
        STORE();
        __syncthreads();
        if (kt + 1 < nk) LOAD(kt + 1);
        #pragma unroll
        for (int ks = 0; ks < 2; ++ks) {
            bf16x8 bf0 = *(const bf16x8*)&Bs[wc*32 +  0 + lq][ks*32 + g*8];
            bf16x8 bf1 = *(const bf16x8*)&Bs[wc*32 + 16 + lq][ks*32 + g*8];
            #pragma unroll
            for (int i = 0; i < 4; ++i) {
                bf16x8 af = *(const bf16x8*)&As[wr*64 + i*16 + lq][ks*32 + g*8];
                acc[i][0] = __builtin_amdgcn_mfma_f32_16x16x32_bf16(af, bf0, acc[i][0], 0, 0, 0);
                acc[i][1] = __builtin_amdgcn_mfma_f32_16x16x32_bf16(af, bf1, acc[i][1], 0, 0, 0);
            }
        }
    }

    float bb[2];
    #pragma unroll
    for (int j = 0; j < 2; ++j) bb[j] = bias[n0 + wc*32 + j*16 + lq];

    #pragma unroll
    for (int i = 0; i < 4; ++i) {
        const int mb = m0 + wr*64 + i*16 + 4*g;
        #pragma unroll
        for (int j = 0; j < 2; ++j) {
            const int n = n0 + wc*32 + j*16 + lq;
            f32x4 v = acc[i][j];
            #pragma unroll
            for (int r = 0; r < 4; ++r) v[r] = (v[r] + bb[j]) * oscale;
            if (mode == 0) {
                float* Cf = (float*)Cv;
                #pragma unroll
                for (int r = 0; r < 4; ++r) Cf[(size_t)(mb + r)*N + n] = v[r];
            } else if (mode == 1) {
                unsigned short* Cb = (unsigned short*)Cv;
                #pragma unroll
                for (int r = 0; r < 4; ++r) Cb[(size_t)(mb + r)*N + n] = f2bf(v[r]);
            } else if (mode == 3) {
                unsigned short* Cb = (unsigned short*)Cv;
                #pragma unroll
                for (int r = 0; r < 4; ++r) Cb[(size_t)(mb + r)*N + n] = f2bf(fmaxf(v[r], 0.f));
            } else if (mode == 4) {
                unsigned short* Cb = (unsigned short*)Cv;
                const int bI = mb / L, kk = mb % L;
                const int hh = n >> 5, d = n & 31;
                const int t2 = kk >> 5, dc = d >> 4, hi2 = (d >> 3) & 1;
                unsigned short* base = Cb
                    + ((size_t)(((bI*NH + hh)*(L >> 5) + t2)*2 + dc))*512
                    + ((kk & 31) + 32*hi2)*8 + (d & 7);
                base[0]  = f2bf(v[0]); base[8]  = f2bf(v[1]);
                base[16] = f2bf(v[2]); base[24] = f2bf(v[3]);
            } else {
                // mode 5: V fragment-major (contiguous ushort4)
                unsigned short* Cb = (unsigned short*)Cv;
                const int bI = mb / L, kk = mb % L;
                const int hh = n >> 5, d = n & 31;
                const int t = kk >> 6, oct = (kk >> 3) & 7;
                const int c = oct >> 1, hiV = oct & 1;
                ushort4 pk;
                pk.x = f2bf(v[0]); pk.y = f2bf(v[1]); pk.z = f2bf(v[2]); pk.w = f2bf(v[3]);
                *(ushort4*)(Cb
                    + ((size_t)(((bI*NH + hh)*(L >> 6) + t)*4 + c))*512
                    + (d + 32*hiV)*8 + (kk & 7)) = pk;
            }
        }
    }
}

// XCD-chunked swizzle over a 2D (nx,ny) grid slice; requires (nx*ny)%8==0.
static __device__ inline void xcd_swz(int d, int nx, int nxy, int& bx, int& by)
{
    const int w = (d & 7) * (nxy >> 3) + (d >> 3);
    bx = w % nx; by = w / nx;
}

__global__ __launch_bounds__(256) void gemm_mfma(const unsigned short* __restrict__ A,
    const unsigned short* __restrict__ W, const float* __restrict__ bias,
    void* __restrict__ C, int M, int N, int K, int mode, int L)
{
    int bx, by;
    xcd_swz(blockIdx.y*gridDim.x + blockIdx.x, gridDim.x, gridDim.x*gridDim.y, bx, by);
    gemm_core(A, W, bias, C, M, N, K, mode, L, 1.f, bx, by);
}

// fused Q/K/V projections: blockIdx.z selects which. Q pre-scaled by
// log2(e)/sqrt(32); K/V written fragment-major for register-direct attention.
__global__ __launch_bounds__(256) void qkv_mfma(const unsigned short* __restrict__ Aq,
    const unsigned short* __restrict__ Akv,
    const unsigned short* __restrict__ Wq, const float* __restrict__ bq,
    const unsigned short* __restrict__ Wk, const float* __restrict__ bk,
    const unsigned short* __restrict__ Wv, const float* __restrict__ bv,
    void* __restrict__ qo, void* __restrict__ ko, void* __restrict__ vo,
    int Mq, int Mkv, int L)
{
    const int z = blockIdx.z;
    const unsigned short* A = (z == 0) ? Aq : Akv;
    const unsigned short* W = (z == 0) ? Wq : ((z == 1) ? Wk : Wv);
    const float* bb = (z == 0) ? bq : ((z == 1) ? bk : bv);
    void* C = (z == 0) ? qo : ((z == 1) ? ko : vo);
    const int M = (z == 0) ? Mq : Mkv;
    const int mode = (z == 0) ? 1 : ((z == 1) ? 4 : 5);
    const float sc = (z == 0) ? 0.25504082364238727f : 1.f;   // log2(e)/sqrt(32)
    int bx, by;
    xcd_swz(blockIdx.y*gridDim.x + blockIdx.x, gridDim.x, gridDim.x*gridDim.y, bx, by);
    if (by * 128 >= M) return;
    gemm_core(A, W, bb, C, M, HID, HID, mode, L, sc, bx, by);
}

// ---------------- fused MFMA attention v6 ------------------------------------
// Register-dataflow flash attention: 32x32x16 MFMA, max-free softmax (Q
// pre-scaled), in-register P via cvt_pk + permlane32_swap. K/V come from
// fragment-major global layouts (KF/VF) so every operand load is ONE
// wave-contiguous 1KB global_load_dwordx4. No LDS staging, no barriers.
__global__ __launch_bounds__(256) void attn_mfma(const unsigned short* __restrict__ Qb,
    const unsigned short* __restrict__ KF, const unsigned short* __restrict__ VF,
    unsigned short* __restrict__ O, int Lk)
{
    __shared__ float Ll[4][32];
    const int orig = blockIdx.x;
    const int sw = (orig & 7) * 128 + (orig >> 3);   // XCD-chunk swizzle (1024%8==0)
    const int qt = sw & 3;
    const int h  = (sw >> 2) & 7;
    const int b  = sw >> 5;
    const int tid = threadIdx.x, w = tid >> 6, lane = tid & 63;
    const int q32 = lane & 31, hi = lane >> 5;

    // Q fragments (B-operand): lane -> (q=q32, d = dc*16 + hi*8 ..+7)
    const unsigned short* qp = Qb + ((size_t)(b*NA + qt*128 + w*32 + q32))*HID + h*DH + hi*8;
    bf16x8 qf0 = *(const bf16x8*)qp;
    bf16x8 qf1 = *(const bf16x8*)(qp + 16);

    const unsigned short* Kf = KF + (size_t)((b*NH + h)*(Lk >> 5)*2)*512 + lane*8;
    const unsigned short* Vf = VF + (size_t)((b*NH + h)*(Lk >> 6)*4)*512 + lane*8;

    f32x16 o_acc = ZERO16;
    float lacc = 0.f;

    bf16x8 kfA[4], kfB[4], vfT[4];
    auto LOADK = [&](int t, bf16x8* kd) {
        #pragma unroll
        for (int f = 0; f < 4; ++f)
            kd[f] = *(const bf16x8*)(Kf + (size_t)(t*4 + f)*512);
    };
    auto STEP = [&](const bf16x8* kf, int t) {
        #pragma unroll
        for (int c = 0; c < 4; ++c)
            vfT[c] = *(const bf16x8*)(Vf + (size_t)(t*4 + c)*512);
        f32x16 st0 = ZERO16, st1 = ZERO16;
        st0 = __builtin_amdgcn_mfma_f32_32x32x16_bf16(kf[0], qf0, st0, 0, 0, 0);
        st0 = __builtin_amdgcn_mfma_f32_32x32x16_bf16(kf[1], qf1, st0, 0, 0, 0);
        st1 = __builtin_amdgcn_mfma_f32_32x32x16_bf16(kf[2], qf0, st1, 0, 0, 0);
        st1 = __builtin_amdgcn_mfma_f32_32x32x16_bf16(kf[3], qf1, st1, 0, 0, 0);
        bf16x8 pa[4];
        float lp = 0.f;
        #pragma unroll
        for (int c = 0; c < 4; ++c) {
            const f32x16& s = (c < 2) ? st0 : st1;
            const int rb = (c & 1) * 8;
            float p0 = __builtin_amdgcn_exp2f(s[rb+0]);
            float p1 = __builtin_amdgcn_exp2f(s[rb+1]);
            float p2 = __builtin_amdgcn_exp2f(s[rb+2]);
            float p3 = __builtin_amdgcn_exp2f(s[rb+3]);
            float p4 = __builtin_amdgcn_exp2f(s[rb+4]);
            float p5 = __builtin_amdgcn_exp2f(s[rb+5]);
            float p6 = __builtin_amdgcn_exp2f(s[rb+6]);
            float p7 = __builtin_amdgcn_exp2f(s[rb+7]);
            lp += (p0+p1) + (p2+p3) + (p4+p5) + (p6+p7);
            unsigned A1 = cvtpk(p0, p1), A2 = cvtpk(p2, p3);
            unsigned B1 = cvtpk(p4, p5), B2 = cvtpk(p6, p7);
            auto r1 = __builtin_amdgcn_permlane32_swap(A1, B1, false, false);
            auto r2 = __builtin_amdgcn_permlane32_swap(A2, B2, false, false);
            u32x4 pw; pw[0] = r1[0]; pw[1] = r2[0]; pw[2] = r1[1]; pw[3] = r2[1];
            __builtin_memcpy(&pa[c], &pw, 16);
        }
        lacc += lp;
        #pragma unroll
        for (int c = 0; c < 4; ++c)
            o_acc = __builtin_amdgcn_mfma_f32_32x32x16_bf16(pa[c], vfT[c], o_acc, 0, 0, 0);
    };

    const int nt = Lk >> 6;   // 8 or 16 (even)
    LOADK(0, kfA);
    for (int t = 0; t < nt; t += 2) {
        LOADK(t + 1, kfB);
        STEP(kfA, t);
        if (t + 2 < nt) LOADK(t + 2, kfA);
        STEP(kfB, t + 1);
    }

    float lt = lacc + __shfl_xor(lacc, 32);
    float linv = 1.f / lt;
    if (hi == 0) Ll[w][q32] = linv;
    f32x4 li[4];
    #pragma unroll
    for (int jg = 0; jg < 4; ++jg) li[jg] = *(const f32x4*)&Ll[w][jg*8 + hi*4];

    unsigned short* Op = O + ((size_t)(b*NA + qt*128 + w*32))*HID + h*DH + q32;
    #pragma unroll
    for (int jg = 0; jg < 4; ++jg) {
        #pragma unroll
        for (int r2 = 0; r2 < 4; ++r2) {
            const int q = jg*8 + hi*4 + r2;
            Op[(size_t)q*HID] = f2bf(o_acc[jg*4 + r2] * li[jg][r2]);
        }
    }
}

// ---------------- residual add + LayerNorm (wave per row, bf16 delta) -------
__global__ __launch_bounds__(256) void add_ln(float* __restrict__ x,
    const unsigned short* __restrict__ t, const float* __restrict__ g,
    const float* __restrict__ bt, unsigned short* __restrict__ xb)
{
    const int row = blockIdx.x*4 + (threadIdx.x >> 6);
    const int lane = threadIdx.x & 63;
    const size_t base = (size_t)row*HID + lane*4;
    float4 v = *(const float4*)(x + base);
    ushort4 tu = *(const ushort4*)(t + base);
    v.x += bf2f(tu.x); v.y += bf2f(tu.y); v.z += bf2f(tu.z); v.w += bf2f(tu.w);
    float s = v.x + v.y + v.z + v.w;
    #pragma unroll
    for (int o = 32; o > 0; o >>= 1) s += __shfl_xor(s, o);
    float mean = s * (1.f/256.f);
    float4 d = {v.x - mean, v.y - mean, v.z - mean, v.w - mean};
    float q2 = d.x*d.x + d.y*d.y + d.z*d.z + d.w*d.w;
    #pragma unroll
    for (int o = 32; o > 0; o >>= 1) q2 += __shfl_xor(q2, o);
    float rs = rsqrtf(q2*(1.f/256.f) + 1e-5f);
    float4 gv = *(const float4*)(g + lane*4);
    float4 bv = *(const float4*)(bt + lane*4);
    float4 ov;
    ov.x = d.x*rs*gv.x + bv.x; ov.y = d.y*rs*gv.y + bv.y;
    ov.z = d.z*rs*gv.z + bv.z; ov.w = d.w*rs*gv.w + bv.w;
    *(float4*)(x + base) = ov;
    ushort4 pk;
    pk.x = f2bf(ov.x); pk.y = f2bf(ov.y); pk.z = f2bf(ov.z); pk.w = f2bf(ov.w);
    *(ushort4*)(xb + base) = pk;
}

// ---------------- pooling: row norms (wave per row) -------------------------
__global__ __launch_bounds__(256) void norms_k(const float* __restrict__ x,
    float* __restrict__ nw)
{
    const int row = blockIdx.x*4 + (threadIdx.x >> 6);
    const int lane = threadIdx.x & 63;
    float4 v = *(const float4*)(x + (size_t)row*HID + lane*4);
    float s = v.x*v.x + v.y*v.y + v.z*v.z + v.w*v.w;
    #pragma unroll
    for (int o = 32; o > 0; o >>= 1) s += __shfl_xor(s, o);
    if (lane == 0) nw[row] = sqrtf(s);
}

// ---------------- pooling: softmax-weighted sum over rows -------------------
__global__ __launch_bounds__(256) void pooled_k(const float* __restrict__ x,
    const float* __restrict__ nw, float* __restrict__ pooled)
{
    __shared__ float sw[NA];
    __shared__ float red[256];
    __shared__ float part[8][33];
    const int b = blockIdx.x, hc = blockIdx.y;
    const int tid = threadIdx.x;
    const float* nb = nw + (size_t)b*NA;
    float v0 = nb[tid], v1 = nb[tid + 256];
    red[tid] = fmaxf(v0, v1); __syncthreads();
    for (int s = 128; s > 0; s >>= 1) { if (tid < s) red[tid] = fmaxf(red[tid], red[tid+s]); __syncthreads(); }
    float mx = red[0]; __syncthreads();
    float e0 = __expf(v0 - mx), e1 = __expf(v1 - mx);
    sw[tid] = e0; sw[tid + 256] = e1;
    red[tid] = e0 + e1; __syncthreads();
    for (int s = 128; s > 0; s >>= 1) { if (tid < s) red[tid] += red[tid+s]; __syncthreads(); }
    float inv = 1.f / red[0];
    __syncthreads();
    const int ng = tid >> 5, col = tid & 31;
    const float* xp = x + (size_t)b*NA*HID + hc*32 + col;
    float acc = 0.f;
    for (int n = ng; n < NA; n += 8)
        acc += sw[n] * xp[(size_t)n*HID];
    part[ng][col] = acc;
    __syncthreads();
    if (tid < 32) {
        float s = 0.f;
        #pragma unroll
        for (int i = 0; i < 8; ++i) s += part[i][tid];
        pooled[(size_t)b*HID + hc*32 + tid] = s * inv;
    }
}

// ---------------- FC head ---------------------------------------------------
__global__ __launch_bounds__(256) void head_k(const float* __restrict__ pooled,
    const float* __restrict__ fc1w, const float* __restrict__ fc1b,
    const float* __restrict__ fc2w, const float* __restrict__ fc2b,
    float* __restrict__ out)
{
    __shared__ float p[HID];
    __shared__ float a1[HID];
    const int b = blockIdx.x, tid = threadIdx.x;
    p[tid] = pooled[(size_t)b*HID + tid];
    __syncthreads();
    float s1 = fc1b[tid];
    const float* w1 = fc1w + (size_t)tid*HID;
    for (int k2 = 0; k2 < HID; k2 += 4) {
        float4 w = *(const float4*)(w1 + k2);
        s1 += p[k2]*w.x + p[k2+1]*w.y + p[k2+2]*w.z + p[k2+3]*w.w;
    }
    a1[tid] = fmaxf(s1, 0.f);
    __syncthreads();
    if (tid < 2) {
        float s2 = fc2b[tid];
        const float* w2 = fc2w + (size_t)tid*HID;
        for (int k2 = 0; k2 < HID; ++k2) s2 += a1[k2] * w2[k2];
        out[b*2 + tid] = s2;
    }
}

// ---------------- launch ----------------------------------------------------
extern "C" void kernel_launch(void* const* d_in, const int* in_sizes, int n_in,
                              void* d_out, int out_size, void* d_ws, size_t ws_size,
                              hipStream_t stream)
{
    const float* trg  = (const float*)d_in[0];
    const float* src  = (const float*)d_in[1];
    const float* ft_w = (const float*)d_in[2];
    const float* ft_b = (const float*)d_in[3];
    const float* ln_g = (const float*)d_in[4];
    const float* ln_b = (const float*)d_in[5];
    const float* sa_wq = (const float*)d_in[6];  const float* sa_bq = (const float*)d_in[7];
    const float* sa_wk = (const float*)d_in[8];  const float* sa_bk = (const float*)d_in[9];
    const float* sa_wv = (const float*)d_in[10]; const float* sa_bv = (const float*)d_in[11];
    const float* sa_wf = (const float*)d_in[12]; const float* sa_bf = (const float*)d_in[13];
    const float* ea_wq = (const float*)d_in[14]; const float* ea_bq = (const float*)d_in[15];
    const float* ea_wk = (const float*)d_in[16]; const float* ea_bk = (const float*)d_in[17];
    const float* ea_wv = (const float*)d_in[18]; const float* ea_bv = (const float*)d_in[19];
    const float* ea_wf = (const float*)d_in[20]; const float* ea_bf = (const float*)d_in[21];
    const float* pf_w1 = (const float*)d_in[22]; const float* pf_b1 = (const float*)d_in[23];
    const float* pf_w2 = (const float*)d_in[24]; const float* pf_b2 = (const float*)d_in[25];
    const float* fc1w  = (const float*)d_in[26]; const float* fc1b  = (const float*)d_in[27];
    const float* fc2w  = (const float*)d_in[28]; const float* fc2b  = (const float*)d_in[29];
    float* out = (float*)d_out;

    const size_t NTOK = (size_t)B_*NA;    // 16384
    const size_t NSRC = (size_t)B_*NP;    // 32768
    float* ws = (float*)d_ws;
    float* x  = ws;                        // [NTOK,HID] fp32 master
    float* nw = x + NTOK*HID;              // [NTOK] row norms
    float* pooled = nw + NTOK;             // [B_,HID]
    unsigned short* ub   = (unsigned short*)(pooled + B_*HID); // [NTOK,HID] bf16 proj-out
    unsigned short* xb   = ub + NTOK*HID;                      // [NTOK,HID] bf16 shadow
    unsigned short* tb   = xb + NTOK*HID;                      // [NTOK,HID] bf16 attn-out
    unsigned short* srcb = tb + NTOK*HID;                      // [NSRC,HID] bf16
    unsigned short* qb   = srcb + NSRC*HID;                    // [NTOK,HID] bf16
    unsigned short* kb   = qb + NTOK*HID;                      // KF fragment-major bf16
    unsigned short* vTb  = kb + NSRC*HID;                      // VF fragment-major bf16
    unsigned short* wb   = vTb + NSRC*HID;                     // 2097152 bf16 weights
    unsigned short* hb   = qb;             // [NTOK,PF] bf16 aliases qb..vTb

    // pre-converted weight pointers
    unsigned short* saq_b = wb;
    unsigned short* sak_b = wb +  131072;
    unsigned short* sav_b = wb +  262144;
    unsigned short* saf_b = wb +  393216;
    unsigned short* eaq_b = wb +  524288;
    unsigned short* eak_b = wb +  655360;
    unsigned short* eav_b = wb +  786432;
    unsigned short* eaf_b = wb +  917504;
    unsigned short* pw1_b = wb + 1048576;
    unsigned short* pw2_b = wb + 1572864;

    const int M = (int)NTOK;
    dim3 blk(256);

    cvt_w<<<dim3(64, 1, 10), blk, 0, stream>>>(sa_wq, sa_wk, sa_wv, sa_wf,
        ea_wq, ea_wk, ea_wv, ea_wf, pf_w1, pf_w2, wb);
    ft_kernel<<<M/32, blk, 0, stream>>>(trg, ft_w, ft_b, x, xb);
    cvt_bf16<<<1024, blk, 0, stream>>>(src, srcb, (int)(NSRC*HID/8));

    for (int l = 0; l < 2; ++l) {
        const size_t wo = (size_t)l*HID*HID, bo = (size_t)l*HID;
        // ---- self attention ----
        qkv_mfma<<<dim3(HID/64, M/128, 3), blk, 0, stream>>>(xb, xb,
            saq_b+wo, sa_bq+bo, sak_b+wo, sa_bk+bo, sav_b+wo, sa_bv+bo,
            qb, kb, vTb, M, M, NA);
        attn_mfma<<<dim3(1024), blk, 0, stream>>>(qb, kb, vTb, tb, NA);
        gemm_mfma<<<dim3(HID/64, M/128), blk, 0, stream>>>(tb, saf_b+wo, sa_bf+bo, ub, M, HID, HID, 1, 0);
        add_ln<<<M/4, blk, 0, stream>>>(x, ub, ln_g+bo, ln_b+bo, xb);
        // ---- cross attention ----
        qkv_mfma<<<dim3(HID/64, (int)NSRC/128, 3), blk, 0, stream>>>(xb, srcb,
            eaq_b+wo, ea_bq+bo, eak_b+wo, ea_bk+bo, eav_b+wo, ea_bv+bo,
            qb, kb, vTb, M, (int)NSRC, NP);
        attn_mfma<<<dim3(1024), blk, 0, stream>>>(qb, kb, vTb, tb, NP);
        gemm_mfma<<<dim3(HID/64, M/128), blk, 0, stream>>>(tb, eaf_b+wo, ea_bf+bo, ub, M, HID, HID, 1, 0);
        add_ln<<<M/4, blk, 0, stream>>>(x, ub, ln_g+bo, ln_b+bo, xb);
        // ---- feed-forward ----
        gemm_mfma<<<dim3(PF/64, M/128), blk, 0, stream>>>(xb, pw1_b+(size_t)l*PF*HID, pf_b1+(size_t)l*PF, hb, M, PF, HID, 3, 0);
        gemm_mfma<<<dim3(HID/64, M/128), blk, 0, stream>>>(hb, pw2_b+(size_t)l*HID*PF, pf_b2+bo, ub, M, HID, PF, 1, 0);
        add_ln<<<M/4, blk, 0, stream>>>(x, ub, ln_g+bo, ln_b+bo, xb);
    }

    norms_k<<<M/4, blk, 0, stream>>>(x, nw);
    pooled_k<<<dim3(B_, 8), blk, 0, stream>>>(x, nw, pooled);
    head_k<<<B_, blk, 0, stream>>>(pooled, fc1w, fc1b, fc2w, fc2b, out);
}

// Round 11
// 443.091 us; speedup vs baseline: 1.2772x; 1.0027x over previous
//
#include <hip/hip_runtime.h>
#include <hip/hip_bf16.h>
#include <math.h>

#define B_   32
#define NA   512
#define NP   1024
#define HID  256
#define NH   8
#define DH   32
#define PF   1024

typedef short bf16x8 __attribute__((ext_vector_type(8)));
typedef float f32x4  __attribute__((ext_vector_type(4)));
typedef float f32x16 __attribute__((ext_vector_type(16)));
typedef unsigned u32x4 __attribute__((ext_vector_type(4)));

#define ZERO16 {0.f,0.f,0.f,0.f,0.f,0.f,0.f,0.f,0.f,0.f,0.f,0.f,0.f,0.f,0.f,0.f}

static __device__ inline unsigned short f2bf(float f) {
    __hip_bfloat16 h = __float2bfloat16(f);   // RNE; pairs fuse to v_cvt_pk_bf16_f32
    unsigned short u;
    __builtin_memcpy(&u, &h, 2);
    return u;
}
static __device__ inline float bf2f(unsigned short u) {
    unsigned x = ((unsigned)u) << 16;
    return __uint_as_float(x);
}
static __device__ inline unsigned cvtpk(float lo, float hi) {
    return (unsigned)f2bf(lo) | ((unsigned)f2bf(hi) << 16);
}
static __device__ inline bf16x8 pack8(float4 a, float4 b) {
    bf16x8 r;
    r[0] = (short)f2bf(a.x); r[1] = (short)f2bf(a.y);
    r[2] = (short)f2bf(a.z); r[3] = (short)f2bf(a.w);
    r[4] = (short)f2bf(b.x); r[5] = (short)f2bf(b.y);
    r[6] = (short)f2bf(b.z); r[7] = (short)f2bf(b.w);
    return r;
}
// async global->LDS, 16B per lane. LDS dest is wave-uniform base + lane*16.
static __device__ inline void gload16(const unsigned short* g, unsigned short* l) {
    __builtin_amdgcn_global_load_lds(
        (const __attribute__((address_space(1))) void*)g,
        (__attribute__((address_space(3))) void*)l, 16, 0, 0);
}

// ---------------- feature transform: x = trg @ ft_w.T + ft_b (fp32 + bf16) --
__global__ __launch_bounds__(256) void ft_kernel(const float* __restrict__ trg,
    const float* __restrict__ w, const float* __restrict__ b,
    float* __restrict__ out, unsigned short* __restrict__ outb)
{
    __shared__ float Ws[256][35];
    int tid = threadIdx.x;
    for (int k = 0; k < 34; ++k) Ws[tid][k] = w[tid*34 + k];
    float bias = b[tid];
    __syncthreads();
    int m0 = blockIdx.x * 32;
    for (int r = 0; r < 32; ++r) {
        int m = m0 + r;
        const float* tr = trg + (size_t)m*34;
        float acc = bias;
        #pragma unroll
        for (int k = 0; k < 34; ++k) acc += tr[k] * Ws[tid][k];
        out [(size_t)m*HID + tid] = acc;
        outb[(size_t)m*HID + tid] = f2bf(acc);
    }
}

// ---------------- fp32 -> bf16 bulk convert ---------------------------------
__global__ __launch_bounds__(256) void cvt_bf16(const float* __restrict__ in,
    unsigned short* __restrict__ outb, int n8)
{
    int i = blockIdx.x*256 + threadIdx.x;
    int stride = gridDim.x*256;
    for (; i < n8; i += stride) {
        float4 a = *(const float4*)(in + (size_t)i*8);
        float4 b = *(const float4*)(in + (size_t)i*8 + 4);
        *(bf16x8*)(outb + (size_t)i*8) = pack8(a, b);
    }
}

// ---------------- weight pre-convert (10 tensors, one launch) ---------------
__global__ __launch_bounds__(256) void cvt_w(
    const float* __restrict__ s0, const float* __restrict__ s1,
    const float* __restrict__ s2, const float* __restrict__ s3,
    const float* __restrict__ s4, const float* __restrict__ s5,
    const float* __restrict__ s6, const float* __restrict__ s7,
    const float* __restrict__ s8, const float* __restrict__ s9,
    unsigned short* __restrict__ dst)
{
    const int z = blockIdx.z;
    const float* src;
    switch (z) {
        case 0: src = s0; break; case 1: src = s1; break;
        case 2: src = s2; break; case 3: src = s3; break;
        case 4: src = s4; break; case 5: src = s5; break;
        case 6: src = s6; break; case 7: src = s7; break;
        case 8: src = s8; break; default: src = s9; break;
    }
    const int n8 = (z < 8) ? 16384 : 65536;
    const size_t off = (z < 8) ? (size_t)z*131072 : (1048576u + (size_t)(z-8)*524288);
    unsigned short* o = dst + off;
    int i = blockIdx.x*256 + threadIdx.x;
    const int stride = gridDim.x*256;
    for (; i < n8; i += stride) {
        float4 a = *(const float4*)(src + (size_t)i*8);
        float4 b = *(const float4*)(src + (size_t)i*8 + 4);
        *(bf16x8*)(o + (size_t)i*8) = pack8(a, b);
    }
}

// ---------------- bf16 MFMA GEMM core v3 (128x64 tile, gload_lds) -----------
// C[M,N] = A[M,K] @ W[N,K]^T + bias. A, W bf16.
// Staging: global_load_lds width=16 into LINEAR [rows][64] LDS, with the
// column XOR-swizzle applied on the per-lane GLOBAL source address
// (csrc = cdst ^ ((row&7)*8)); ds_reads apply the same XOR -> balanced banks.
// Double-buffered, ONE __syncthreads per k-tile (its vmcnt/lgkm drain makes
// next tile ready and protects the buffer being overwritten).
// mode: 0 fp32 out; 1 bf16 out; 3 bf16 relu out;
// 4 bf16 K-fragment-major; 5 bf16 V-fragment-major (see attention).
static __device__ inline void gemm_core(const unsigned short* __restrict__ Ab,
    const unsigned short* __restrict__ Wb, const float* __restrict__ bias,
    void* __restrict__ Cv, int M, int N, int K, int mode, int L, float oscale,
    int bx, int by)
{
    __shared__ __attribute__((aligned(16))) unsigned short As[2][128*64]; // 32KB
    __shared__ __attribute__((aligned(16))) unsigned short Ws[2][64*64];  // 16KB
    const int tid = threadIdx.x;
    const int wave = tid >> 6, lane = tid & 63, lq = lane & 15, g = lane >> 4;
    const int wr = wave >> 1, wc = wave & 1;
    const int m0 = by * 128, n0 = bx * 64;

    const int srow = lane >> 3;                         // row within 8-row chunk
    const int scol = ((lane & 7) ^ ((lane >> 3) & 7)) * 8;  // pre-swizzled src col
    const int cswz = (lq & 7) * 8;                      // read-side XOR

    f32x4 acc[4][2] = {};

    auto STAGE = [&](int kt, int buf) {
        const int k0 = kt * 64;
        #pragma unroll
        for (int c = 0; c < 4; ++c) {
            const int row = wave*32 + c*8;
            gload16(Ab + (size_t)(m0 + row + srow)*K + k0 + scol,
                    &As[buf][row*64]);
        }
        #pragma unroll
        for (int c = 0; c < 2; ++c) {
            const int row = wave*16 + c*8;
            gload16(Wb + (size_t)(n0 + row + srow)*K + k0 + scol,
                    &Ws[buf][row*64]);
        }
    };

    const int nk = K / 64;
    STAGE(0, 0);
    __syncthreads();                       // drains vmcnt(0): tile 0 ready
    for (int kt = 0; kt < nk; ++kt) {
        const int cur = kt & 1;
        if (kt + 1 < nk) STAGE(kt + 1, cur ^ 1);
        const unsigned short* Ac = &As[cur][0];
        const unsigned short* Wc = &Ws[cur][0];
        #pragma unroll
        for (int ks = 0; ks < 2; ++ks) {
            const int co = (ks*32 + g*8) ^ cswz;
            bf16x8 bf0 = *(const bf16x8*)&Wc[(wc*32 +  0 + lq)*64 + co];
            bf16x8 bf1 = *(const bf16x8*)&Wc[(wc*32 + 16 + lq)*64 + co];
            #pragma unroll
            for (int i = 0; i < 4; ++i) {
                bf16x8 af = *(const bf16x8*)&Ac[(wr*64 + i*16 + lq)*64 + co];
                acc[i][0] = __builtin_amdgcn_mfma_f32_16x16x32_bf16(af, bf0, acc[i][0], 0, 0, 0);
                acc[i][1] = __builtin_amdgcn_mfma_f32_16x16x32_bf16(af, bf1, acc[i][1], 0, 0, 0);
            }
        }
        __syncthreads();                   // next tile landed; reads drained
    }

    float bb[2];
    #pragma unroll
    for (int j = 0; j < 2; ++j) bb[j] = bias[n0 + wc*32 + j*16 + lq];

    #pragma unroll
    for (int i = 0; i < 4; ++i) {
        const int mb = m0 + wr*64 + i*16 + 4*g;
        #pragma unroll
        for (int j = 0; j < 2; ++j) {
            const int n = n0 + wc*32 + j*16 + lq;
            f32x4 v = acc[i][j];
            #pragma unroll
            for (int r = 0; r < 4; ++r) v[r] = (v[r] + bb[j]) * oscale;
            if (mode == 0) {
                float* Cf = (float*)Cv;
                #pragma unroll
                for (int r = 0; r < 4; ++r) Cf[(size_t)(mb + r)*N + n] = v[r];
            } else if (mode == 1) {
                unsigned short* Cb = (unsigned short*)Cv;
                #pragma unroll
                for (int r = 0; r < 4; ++r) Cb[(size_t)(mb + r)*N + n] = f2bf(v[r]);
            } else if (mode == 3) {
                unsigned short* Cb = (unsigned short*)Cv;
                #pragma unroll
                for (int r = 0; r < 4; ++r) Cb[(size_t)(mb + r)*N + n] = f2bf(fmaxf(v[r], 0.f));
            } else if (mode == 4) {
                unsigned short* Cb = (unsigned short*)Cv;
                const int bI = mb / L, kk = mb % L;
                const int hh = n >> 5, d = n & 31;
                const int t2 = kk >> 5, dc = d >> 4, hi2 = (d >> 3) & 1;
                unsigned short* base = Cb
                    + ((size_t)(((bI*NH + hh)*(L >> 5) + t2)*2 + dc))*512
                    + ((kk & 31) + 32*hi2)*8 + (d & 7);
                base[0]  = f2bf(v[0]); base[8]  = f2bf(v[1]);
                base[16] = f2bf(v[2]); base[24] = f2bf(v[3]);
            } else {
                // mode 5: V fragment-major (contiguous ushort4)
                unsigned short* Cb = (unsigned short*)Cv;
                const int bI = mb / L, kk = mb % L;
                const int hh = n >> 5, d = n & 31;
                const int t = kk >> 6, oct = (kk >> 3) & 7;
                const int c = oct >> 1, hiV = oct & 1;
                ushort4 pk;
                pk.x = f2bf(v[0]); pk.y = f2bf(v[1]); pk.z = f2bf(v[2]); pk.w = f2bf(v[3]);
                *(ushort4*)(Cb
                    + ((size_t)(((bI*NH + hh)*(L >> 6) + t)*4 + c))*512
                    + (d + 32*hiV)*8 + (kk & 7)) = pk;
            }
        }
    }
}

// XCD-chunked swizzle over a 2D (nx,ny) grid slice; requires (nx*ny)%8==0.
static __device__ inline void xcd_swz(int d, int nx, int nxy, int& bx, int& by)
{
    const int w = (d & 7) * (nxy >> 3) + (d >> 3);
    bx = w % nx; by = w / nx;
}

__global__ __launch_bounds__(256) void gemm_mfma(const unsigned short* __restrict__ A,
    const unsigned short* __restrict__ W, const float* __restrict__ bias,
    void* __restrict__ C, int M, int N, int K, int mode, int L)
{
    int bx, by;
    xcd_swz(blockIdx.y*gridDim.x + blockIdx.x, gridDim.x, gridDim.x*gridDim.y, bx, by);
    gemm_core(A, W, bias, C, M, N, K, mode, L, 1.f, bx, by);
}

// fused Q/K/V projections: blockIdx.z selects which. Q pre-scaled by
// log2(e)/sqrt(32); K/V written fragment-major for register-direct attention.
__global__ __launch_bounds__(256) void qkv_mfma(const unsigned short* __restrict__ Aq,
    const unsigned short* __restrict__ Akv,
    const unsigned short* __restrict__ Wq, const float* __restrict__ bq,
    const unsigned short* __restrict__ Wk, const float* __restrict__ bk,
    const unsigned short* __restrict__ Wv, const float* __restrict__ bv,
    void* __restrict__ qo, void* __restrict__ ko, void* __restrict__ vo,
    int Mq, int Mkv, int L)
{
    const int z = blockIdx.z;
    const unsigned short* A = (z == 0) ? Aq : Akv;
    const unsigned short* W = (z == 0) ? Wq : ((z == 1) ? Wk : Wv);
    const float* bb = (z == 0) ? bq : ((z == 1) ? bk : bv);
    void* C = (z == 0) ? qo : ((z == 1) ? ko : vo);
    const int M = (z == 0) ? Mq : Mkv;
    const int mode = (z == 0) ? 1 : ((z == 1) ? 4 : 5);
    const float sc = (z == 0) ? 0.25504082364238727f : 1.f;   // log2(e)/sqrt(32)
    int bx, by;
    xcd_swz(blockIdx.y*gridDim.x + blockIdx.x, gridDim.x, gridDim.x*gridDim.y, bx, by);
    if (by * 128 >= M) return;
    gemm_core(A, W, bb, C, M, HID, HID, mode, L, sc, bx, by);
}

// ---------------- fused MFMA attention v6 ------------------------------------
// Register-dataflow flash attention: 32x32x16 MFMA, max-free softmax (Q
// pre-scaled), in-register P via cvt_pk + permlane32_swap. K/V come from
// fragment-major global layouts (KF/VF) so every operand load is ONE
// wave-contiguous 1KB global_load_dwordx4. No LDS staging, no barriers.
__global__ __launch_bounds__(256) void attn_mfma(const unsigned short* __restrict__ Qb,
    const unsigned short* __restrict__ KF, const unsigned short* __restrict__ VF,
    unsigned short* __restrict__ O, int Lk)
{
    __shared__ float Ll[4][32];
    const int orig = blockIdx.x;
    const int sw = (orig & 7) * 128 + (orig >> 3);   // XCD-chunk swizzle (1024%8==0)
    const int qt = sw & 3;
    const int h  = (sw >> 2) & 7;
    const int b  = sw >> 5;
    const int tid = threadIdx.x, w = tid >> 6, lane = tid & 63;
    const int q32 = lane & 31, hi = lane >> 5;

    // Q fragments (B-operand): lane -> (q=q32, d = dc*16 + hi*8 ..+7)
    const unsigned short* qp = Qb + ((size_t)(b*NA + qt*128 + w*32 + q32))*HID + h*DH + hi*8;
    bf16x8 qf0 = *(const bf16x8*)qp;
    bf16x8 qf1 = *(const bf16x8*)(qp + 16);

    const unsigned short* Kf = KF + (size_t)((b*NH + h)*(Lk >> 5)*2)*512 + lane*8;
    const unsigned short* Vf = VF + (size_t)((b*NH + h)*(Lk >> 6)*4)*512 + lane*8;

    f32x16 o_acc = ZERO16;
    float lacc = 0.f;

    bf16x8 kfA[4], kfB[4], vfT[4];
    auto LOADK = [&](int t, bf16x8* kd) {
        #pragma unroll
        for (int f = 0; f < 4; ++f)
            kd[f] = *(const bf16x8*)(Kf + (size_t)(t*4 + f)*512);
    };
    auto STEP = [&](const bf16x8* kf, int t) {
        #pragma unroll
        for (int c = 0; c < 4; ++c)
            vfT[c] = *(const bf16x8*)(Vf + (size_t)(t*4 + c)*512);
        f32x16 st0 = ZERO16, st1 = ZERO16;
        st0 = __builtin_amdgcn_mfma_f32_32x32x16_bf16(kf[0], qf0, st0, 0, 0, 0);
        st0 = __builtin_amdgcn_mfma_f32_32x32x16_bf16(kf[1], qf1, st0, 0, 0, 0);
        st1 = __builtin_amdgcn_mfma_f32_32x32x16_bf16(kf[2], qf0, st1, 0, 0, 0);
        st1 = __builtin_amdgcn_mfma_f32_32x32x16_bf16(kf[3], qf1, st1, 0, 0, 0);
        bf16x8 pa[4];
        float lp = 0.f;
        #pragma unroll
        for (int c = 0; c < 4; ++c) {
            const f32x16& s = (c < 2) ? st0 : st1;
            const int rb = (c & 1) * 8;
            float p0 = __builtin_amdgcn_exp2f(s[rb+0]);
            float p1 = __builtin_amdgcn_exp2f(s[rb+1]);
            float p2 = __builtin_amdgcn_exp2f(s[rb+2]);
            float p3 = __builtin_amdgcn_exp2f(s[rb+3]);
            float p4 = __builtin_amdgcn_exp2f(s[rb+4]);
            float p5 = __builtin_amdgcn_exp2f(s[rb+5]);
            float p6 = __builtin_amdgcn_exp2f(s[rb+6]);
            float p7 = __builtin_amdgcn_exp2f(s[rb+7]);
            lp += (p0+p1) + (p2+p3) + (p4+p5) + (p6+p7);
            unsigned A1 = cvtpk(p0, p1), A2 = cvtpk(p2, p3);
            unsigned B1 = cvtpk(p4, p5), B2 = cvtpk(p6, p7);
            auto r1 = __builtin_amdgcn_permlane32_swap(A1, B1, false, false);
            auto r2 = __builtin_amdgcn_permlane32_swap(A2, B2, false, false);
            u32x4 pw; pw[0] = r1[0]; pw[1] = r2[0]; pw[2] = r1[1]; pw[3] = r2[1];
            __builtin_memcpy(&pa[c], &pw, 16);
        }
        lacc += lp;
        #pragma unroll
        for (int c = 0; c < 4; ++c)
            o_acc = __builtin_amdgcn_mfma_f32_32x32x16_bf16(pa[c], vfT[c], o_acc, 0, 0, 0);
    };

    const int nt = Lk >> 6;   // 8 or 16 (even)
    LOADK(0, kfA);
    for (int t = 0; t < nt; t += 2) {
        LOADK(t + 1, kfB);
        STEP(kfA, t);
        if (t + 2 < nt) LOADK(t + 2, kfA);
        STEP(kfB, t + 1);
    }

    float lt = lacc + __shfl_xor(lacc, 32);
    float linv = 1.f / lt;
    if (hi == 0) Ll[w][q32] = linv;
    f32x4 li[4];
    #pragma unroll
    for (int jg = 0; jg < 4; ++jg) li[jg] = *(const f32x4*)&Ll[w][jg*8 + hi*4];

    unsigned short* Op = O + ((size_t)(b*NA + qt*128 + w*32))*HID + h*DH + q32;
    #pragma unroll
    for (int jg = 0; jg < 4; ++jg) {
        #pragma unroll
        for (int r2 = 0; r2 < 4; ++r2) {
            const int q = jg*8 + hi*4 + r2;
            Op[(size_t)q*HID] = f2bf(o_acc[jg*4 + r2] * li[jg][r2]);
        }
    }
}

// ---------------- residual add + LayerNorm (wave per row, bf16 delta) -------
__global__ __launch_bounds__(256) void add_ln(float* __restrict__ x,
    const unsigned short* __restrict__ t, const float* __restrict__ g,
    const float* __restrict__ bt, unsigned short* __restrict__ xb)
{
    const int row = blockIdx.x*4 + (threadIdx.x >> 6);
    const int lane = threadIdx.x & 63;
    const size_t base = (size_t)row*HID + lane*4;
    float4 v = *(const float4*)(x + base);
    ushort4 tu = *(const ushort4*)(t + base);
    v.x += bf2f(tu.x); v.y += bf2f(tu.y); v.z += bf2f(tu.z); v.w += bf2f(tu.w);
    float s = v.x + v.y + v.z + v.w;
    #pragma unroll
    for (int o = 32; o > 0; o >>= 1) s += __shfl_xor(s, o);
    float mean = s * (1.f/256.f);
    float4 d = {v.x - mean, v.y - mean, v.z - mean, v.w - mean};
    float q2 = d.x*d.x + d.y*d.y + d.z*d.z + d.w*d.w;
    #pragma unroll
    for (int o = 32; o > 0; o >>= 1) q2 += __shfl_xor(q2, o);
    float rs = rsqrtf(q2*(1.f/256.f) + 1e-5f);
    float4 gv = *(const float4*)(g + lane*4);
    float4 bv = *(const float4*)(bt + lane*4);
    float4 ov;
    ov.x = d.x*rs*gv.x + bv.x; ov.y = d.y*rs*gv.y + bv.y;
    ov.z = d.z*rs*gv.z + bv.z; ov.w = d.w*rs*gv.w + bv.w;
    *(float4*)(x + base) = ov;
    ushort4 pk;
    pk.x = f2bf(ov.x); pk.y = f2bf(ov.y); pk.z = f2bf(ov.z); pk.w = f2bf(ov.w);
    *(ushort4*)(xb + base) = pk;
}

// ---------------- pooling: row norms (wave per row) -------------------------
__global__ __launch_bounds__(256) void norms_k(const float* __restrict__ x,
    float* __restrict__ nw)
{
    const int row = blockIdx.x*4 + (threadIdx.x >> 6);
    const int lane = threadIdx.x & 63;
    float4 v = *(const float4*)(x + (size_t)row*HID + lane*4);
    float s = v.x*v.x + v.y*v.y + v.z*v.z + v.w*v.w;
    #pragma unroll
    for (int o = 32; o > 0; o >>= 1) s += __shfl_xor(s, o);
    if (lane == 0) nw[row] = sqrtf(s);
}

// ---------------- pooling: softmax-weighted sum over rows -------------------
__global__ __launch_bounds__(256) void pooled_k(const float* __restrict__ x,
    const float* __restrict__ nw, float* __restrict__ pooled)
{
    __shared__ float sw[NA];
    __shared__ float red[256];
    __shared__ float part[8][33];
    const int b = blockIdx.x, hc = blockIdx.y;
    const int tid = threadIdx.x;
    const float* nb = nw + (size_t)b*NA;
    float v0 = nb[tid], v1 = nb[tid + 256];
    red[tid] = fmaxf(v0, v1); __syncthreads();
    for (int s = 128; s > 0; s >>= 1) { if (tid < s) red[tid] = fmaxf(red[tid], red[tid+s]); __syncthreads(); }
    float mx = red[0]; __syncthreads();
    float e0 = __expf(v0 - mx), e1 = __expf(v1 - mx);
    sw[tid] = e0; sw[tid + 256] = e1;
    red[tid] = e0 + e1; __syncthreads();
    for (int s = 128; s > 0; s >>= 1) { if (tid < s) red[tid] += red[tid+s]; __syncthreads(); }
    float inv = 1.f / red[0];
    __syncthreads();
    const int ng = tid >> 5, col = tid & 31;
    const float* xp = x + (size_t)b*NA*HID + hc*32 + col;
    float acc = 0.f;
    for (int n = ng; n < NA; n += 8)
        acc += sw[n] * xp[(size_t)n*HID];
    part[ng][col] = acc;
    __syncthreads();
    if (tid < 32) {
        float s = 0.f;
        #pragma unroll
        for (int i = 0; i < 8; ++i) s += part[i][tid];
        pooled[(size_t)b*HID + hc*32 + tid] = s * inv;
    }
}

// ---------------- FC head ---------------------------------------------------
__global__ __launch_bounds__(256) void head_k(const float* __restrict__ pooled,
    const float* __restrict__ fc1w, const float* __restrict__ fc1b,
    const float* __restrict__ fc2w, const float* __restrict__ fc2b,
    float* __restrict__ out)
{
    __shared__ float p[HID];
    __shared__ float a1[HID];
    const int b = blockIdx.x, tid = threadIdx.x;
    p[tid] = pooled[(size_t)b*HID + tid];
    __syncthreads();
    float s1 = fc1b[tid];
    const float* w1 = fc1w + (size_t)tid*HID;
    for (int k2 = 0; k2 < HID; k2 += 4) {
        float4 w = *(const float4*)(w1 + k2);
        s1 += p[k2]*w.x + p[k2+1]*w.y + p[k2+2]*w.z + p[k2+3]*w.w;
    }
    a1[tid] = fmaxf(s1, 0.f);
    __syncthreads();
    if (tid < 2) {
        float s2 = fc2b[tid];
        const float* w2 = fc2w + (size_t)tid*HID;
        for (int k2 = 0; k2 < HID; ++k2) s2 += a1[k2] * w2[k2];
        out[b*2 + tid] = s2;
    }
}

// ---------------- launch ----------------------------------------------------
extern "C" void kernel_launch(void* const* d_in, const int* in_sizes, int n_in,
                              void* d_out, int out_size, void* d_ws, size_t ws_size,
                              hipStream_t stream)
{
    const float* trg  = (const float*)d_in[0];
    const float* src  = (const float*)d_in[1];
    const float* ft_w = (const float*)d_in[2];
    const float* ft_b = (const float*)d_in[3];
    const float* ln_g = (const float*)d_in[4];
    const float* ln_b = (const float*)d_in[5];
    const float* sa_wq = (const float*)d_in[6];  const float* sa_bq = (const float*)d_in[7];
    const float* sa_wk = (const float*)d_in[8];  const float* sa_bk = (const float*)d_in[9];
    const float* sa_wv = (const float*)d_in[10]; const float* sa_bv = (const float*)d_in[11];
    const float* sa_wf = (const float*)d_in[12]; const float* sa_bf = (const float*)d_in[13];
    const float* ea_wq = (const float*)d_in[14]; const float* ea_bq = (const float*)d_in[15];
    const float* ea_wk = (const float*)d_in[16]; const float* ea_bk = (const float*)d_in[17];
    const float* ea_wv = (const float*)d_in[18]; const float* ea_bv = (const float*)d_in[19];
    const float* ea_wf = (const float*)d_in[20]; const float* ea_bf = (const float*)d_in[21];
    const float* pf_w1 = (const float*)d_in[22]; const float* pf_b1 = (const float*)d_in[23];
    const float* pf_w2 = (const float*)d_in[24]; const float* pf_b2 = (const float*)d_in[25];
    const float* fc1w  = (const float*)d_in[26]; const float* fc1b  = (const float*)d_in[27];
    const float* fc2w  = (const float*)d_in[28]; const float* fc2b  = (const float*)d_in[29];
    float* out = (float*)d_out;

    const size_t NTOK = (size_t)B_*NA;    // 16384
    const size_t NSRC = (size_t)B_*NP;    // 32768
    float* ws = (float*)d_ws;
    float* x  = ws;                        // [NTOK,HID] fp32 master
    float* nw = x + NTOK*HID;              // [NTOK] row norms
    float* pooled = nw + NTOK;             // [B_,HID]
    unsigned short* ub   = (unsigned short*)(pooled + B_*HID); // [NTOK,HID] bf16 proj-out
    unsigned short* xb   = ub + NTOK*HID;                      // [NTOK,HID] bf16 shadow
    unsigned short* tb   = xb + NTOK*HID;                      // [NTOK,HID] bf16 attn-out
    unsigned short* srcb = tb + NTOK*HID;                      // [NSRC,HID] bf16
    unsigned short* qb   = srcb + NSRC*HID;                    // [NTOK,HID] bf16
    unsigned short* kb   = qb + NTOK*HID;                      // KF fragment-major bf16
    unsigned short* vTb  = kb + NSRC*HID;                      // VF fragment-major bf16
    unsigned short* wb   = vTb + NSRC*HID;                     // 2097152 bf16 weights
    unsigned short* hb   = qb;             // [NTOK,PF] bf16 aliases qb..vTb

    // pre-converted weight pointers
    unsigned short* saq_b = wb;
    unsigned short* sak_b = wb +  131072;
    unsigned short* sav_b = wb +  262144;
    unsigned short* saf_b = wb +  393216;
    unsigned short* eaq_b = wb +  524288;
    unsigned short* eak_b = wb +  655360;
    unsigned short* eav_b = wb +  786432;
    unsigned short* eaf_b = wb +  917504;
    unsigned short* pw1_b = wb + 1048576;
    unsigned short* pw2_b = wb + 1572864;

    const int M = (int)NTOK;
    dim3 blk(256);

    cvt_w<<<dim3(64, 1, 10), blk, 0, stream>>>(sa_wq, sa_wk, sa_wv, sa_wf,
        ea_wq, ea_wk, ea_wv, ea_wf, pf_w1, pf_w2, wb);
    ft_kernel<<<M/32, blk, 0, stream>>>(trg, ft_w, ft_b, x, xb);
    cvt_bf16<<<1024, blk, 0, stream>>>(src, srcb, (int)(NSRC*HID/8));

    for (int l = 0; l < 2; ++l) {
        const size_t wo = (size_t)l*HID*HID, bo = (size_t)l*HID;
        // ---- self attention ----
        qkv_mfma<<<dim3(HID/64, M/128, 3), blk, 0, stream>>>(xb, xb,
            saq_b+wo, sa_bq+bo, sak_b+wo, sa_bk+bo, sav_b+wo, sa_bv+bo,
            qb, kb, vTb, M, M, NA);
        attn_mfma<<<dim3(1024), blk, 0, stream>>>(qb, kb, vTb, tb, NA);
        gemm_mfma<<<dim3(HID/64, M/128), blk, 0, stream>>>(tb, saf_b+wo, sa_bf+bo, ub, M, HID, HID, 1, 0);
        add_ln<<<M/4, blk, 0, stream>>>(x, ub, ln_g+bo, ln_b+bo, xb);
        // ---- cross attention ----
        qkv_mfma<<<dim3(HID/64, (int)NSRC/128, 3), blk, 0, stream>>>(xb, srcb,
            eaq_b+wo, ea_bq+bo, eak_b+wo, ea_bk+bo, eav_b+wo, ea_bv+bo,
            qb, kb, vTb, M, (int)NSRC, NP);
        attn_mfma<<<dim3(1024), blk, 0, stream>>>(qb, kb, vTb, tb, NP);
        gemm_mfma<<<dim3(HID/64, M/128), blk, 0, stream>>>(tb, eaf_b+wo, ea_bf+bo, ub, M, HID, HID, 1, 0);
        add_ln<<<M/4, blk, 0, stream>>>(x, ub, ln_g+bo, ln_b+bo, xb);
        // ---- feed-forward ----
        gemm_mfma<<<dim3(PF/64, M/128), blk, 0, stream>>>(xb, pw1_b+(size_t)l*PF*HID, pf_b1+(size_t)l*PF, hb, M, PF, HID, 3, 0);
        gemm_mfma<<<dim3(HID/64, M/128), blk, 0, stream>>>(hb, pw2_b+(size_t)l*HID*PF, pf_b2+bo, ub, M, HID, PF, 1, 0);
        add_ln<<<M/4, blk, 0, stream>>>(x, ub, ln_g+bo, ln_b+bo, xb);
    }

    norms_k<<<M/4, blk, 0, stream>>>(x, nw);
    pooled_k<<<dim3(B_, 8), blk, 0, stream>>>(x, nw, pooled);
    head_k<<<B_, blk, 0, stream>>>(pooled, fc1w, fc1b, fc2w, fc2b, out);
}

// Round 12
// 416.480 us; speedup vs baseline: 1.3588x; 1.0639x over previous
//
#include <hip/hip_runtime.h>
#include <hip/hip_bf16.h>
#include <math.h>

#define B_   32
#define NA   512
#define NP   1024
#define HID  256
#define NH   8
#define DH   32
#define PF   1024

typedef short bf16x8 __attribute__((ext_vector_type(8)));
typedef float f32x4  __attribute__((ext_vector_type(4)));
typedef float f32x16 __attribute__((ext_vector_type(16)));
typedef unsigned u32x4 __attribute__((ext_vector_type(4)));

#define ZERO16 {0.f,0.f,0.f,0.f,0.f,0.f,0.f,0.f,0.f,0.f,0.f,0.f,0.f,0.f,0.f,0.f}

static __device__ inline unsigned short f2bf(float f) {
    __hip_bfloat16 h = __float2bfloat16(f);   // RNE; pairs fuse to v_cvt_pk_bf16_f32
    unsigned short u;
    __builtin_memcpy(&u, &h, 2);
    return u;
}
static __device__ inline float bf2f(unsigned short u) {
    unsigned x = ((unsigned)u) << 16;
    return __uint_as_float(x);
}
static __device__ inline unsigned cvtpk(float lo, float hi) {
    return (unsigned)f2bf(lo) | ((unsigned)f2bf(hi) << 16);
}
static __device__ inline bf16x8 pack8(float4 a, float4 b) {
    bf16x8 r;
    r[0] = (short)f2bf(a.x); r[1] = (short)f2bf(a.y);
    r[2] = (short)f2bf(a.z); r[3] = (short)f2bf(a.w);
    r[4] = (short)f2bf(b.x); r[5] = (short)f2bf(b.y);
    r[6] = (short)f2bf(b.z); r[7] = (short)f2bf(b.w);
    return r;
}
// async global->LDS, 16B per lane. LDS dest is wave-uniform base + lane*16.
static __device__ inline void gload16(const unsigned short* g, unsigned short* l) {
    __builtin_amdgcn_global_load_lds(
        (const __attribute__((address_space(1))) void*)g,
        (__attribute__((address_space(3))) void*)l, 16, 0, 0);
}

// ---------------- feature transform: x = trg @ ft_w.T + ft_b (fp32 + bf16) --
__global__ __launch_bounds__(256) void ft_kernel(const float* __restrict__ trg,
    const float* __restrict__ w, const float* __restrict__ b,
    float* __restrict__ out, unsigned short* __restrict__ outb)
{
    __shared__ float Ws[256][35];
    int tid = threadIdx.x;
    for (int k = 0; k < 34; ++k) Ws[tid][k] = w[tid*34 + k];
    float bias = b[tid];
    __syncthreads();
    int m0 = blockIdx.x * 32;
    for (int r = 0; r < 32; ++r) {
        int m = m0 + r;
        const float* tr = trg + (size_t)m*34;
        float acc = bias;
        #pragma unroll
        for (int k = 0; k < 34; ++k) acc += tr[k] * Ws[tid][k];
        out [(size_t)m*HID + tid] = acc;
        outb[(size_t)m*HID + tid] = f2bf(acc);
    }
}

// ---------------- fp32 -> bf16 bulk convert ---------------------------------
__global__ __launch_bounds__(256) void cvt_bf16(const float* __restrict__ in,
    unsigned short* __restrict__ outb, int n8)
{
    int i = blockIdx.x*256 + threadIdx.x;
    int stride = gridDim.x*256;
    for (; i < n8; i += stride) {
        float4 a = *(const float4*)(in + (size_t)i*8);
        float4 b = *(const float4*)(in + (size_t)i*8 + 4);
        *(bf16x8*)(outb + (size_t)i*8) = pack8(a, b);
    }
}

// ---------------- weight pre-convert (10 tensors, one launch) ---------------
__global__ __launch_bounds__(256) void cvt_w(
    const float* __restrict__ s0, const float* __restrict__ s1,
    const float* __restrict__ s2, const float* __restrict__ s3,
    const float* __restrict__ s4, const float* __restrict__ s5,
    const float* __restrict__ s6, const float* __restrict__ s7,
    const float* __restrict__ s8, const float* __restrict__ s9,
    unsigned short* __restrict__ dst)
{
    const int z = blockIdx.z;
    const float* src;
    switch (z) {
        case 0: src = s0; break; case 1: src = s1; break;
        case 2: src = s2; break; case 3: src = s3; break;
        case 4: src = s4; break; case 5: src = s5; break;
        case 6: src = s6; break; case 7: src = s7; break;
        case 8: src = s8; break; default: src = s9; break;
    }
    const int n8 = (z < 8) ? 16384 : 65536;
    const size_t off = (z < 8) ? (size_t)z*131072 : (1048576u + (size_t)(z-8)*524288);
    unsigned short* o = dst + off;
    int i = blockIdx.x*256 + threadIdx.x;
    const int stride = gridDim.x*256;
    for (; i < n8; i += stride) {
        float4 a = *(const float4*)(src + (size_t)i*8);
        float4 b = *(const float4*)(src + (size_t)i*8 + 4);
        *(bf16x8*)(o + (size_t)i*8) = pack8(a, b);
    }
}

// ---------------- bf16 MFMA GEMM core v3 (128x64 tile, gload_lds) -----------
// C[M,N] = A[M,K] @ W[N,K]^T + bias. A, W bf16.
// mode: 1 bf16 out; 3 bf16 relu out; 4 bf16 K-fragment-major;
// 5 bf16 V-fragment-major (see attention).
static __device__ inline void gemm_core(const unsigned short* __restrict__ Ab,
    const unsigned short* __restrict__ Wb, const float* __restrict__ bias,
    void* __restrict__ Cv, int M, int N, int K, int mode, int L, float oscale,
    int bx, int by)
{
    __shared__ __attribute__((aligned(16))) unsigned short As[2][128*64]; // 32KB
    __shared__ __attribute__((aligned(16))) unsigned short Ws[2][64*64];  // 16KB
    const int tid = threadIdx.x;
    const int wave = tid >> 6, lane = tid & 63, lq = lane & 15, g = lane >> 4;
    const int wr = wave >> 1, wc = wave & 1;
    const int m0 = by * 128, n0 = bx * 64;

    const int srow = lane >> 3;                         // row within 8-row chunk
    const int scol = ((lane & 7) ^ ((lane >> 3) & 7)) * 8;  // pre-swizzled src col
    const int cswz = (lq & 7) * 8;                      // read-side XOR

    f32x4 acc[4][2] = {};

    auto STAGE = [&](int kt, int buf) {
        const int k0 = kt * 64;
        #pragma unroll
        for (int c = 0; c < 4; ++c) {
            const int row = wave*32 + c*8;
            gload16(Ab + (size_t)(m0 + row + srow)*K + k0 + scol,
                    &As[buf][row*64]);
        }
        #pragma unroll
        for (int c = 0; c < 2; ++c) {
            const int row = wave*16 + c*8;
            gload16(Wb + (size_t)(n0 + row + srow)*K + k0 + scol,
                    &Ws[buf][row*64]);
        }
    };

    const int nk = K / 64;
    STAGE(0, 0);
    __syncthreads();
    for (int kt = 0; kt < nk; ++kt) {
        const int cur = kt & 1;
        if (kt + 1 < nk) STAGE(kt + 1, cur ^ 1);
        const unsigned short* Ac = &As[cur][0];
        const unsigned short* Wc = &Ws[cur][0];
        #pragma unroll
        for (int ks = 0; ks < 2; ++ks) {
            const int co = (ks*32 + g*8) ^ cswz;
            bf16x8 bf0 = *(const bf16x8*)&Wc[(wc*32 +  0 + lq)*64 + co];
            bf16x8 bf1 = *(const bf16x8*)&Wc[(wc*32 + 16 + lq)*64 + co];
            #pragma unroll
            for (int i = 0; i < 4; ++i) {
                bf16x8 af = *(const bf16x8*)&Ac[(wr*64 + i*16 + lq)*64 + co];
                acc[i][0] = __builtin_amdgcn_mfma_f32_16x16x32_bf16(af, bf0, acc[i][0], 0, 0, 0);
                acc[i][1] = __builtin_amdgcn_mfma_f32_16x16x32_bf16(af, bf1, acc[i][1], 0, 0, 0);
            }
        }
        __syncthreads();
    }

    float bb[2];
    #pragma unroll
    for (int j = 0; j < 2; ++j) bb[j] = bias[n0 + wc*32 + j*16 + lq];

    #pragma unroll
    for (int i = 0; i < 4; ++i) {
        const int mb = m0 + wr*64 + i*16 + 4*g;
        #pragma unroll
        for (int j = 0; j < 2; ++j) {
            const int n = n0 + wc*32 + j*16 + lq;
            f32x4 v = acc[i][j];
            #pragma unroll
            for (int r = 0; r < 4; ++r) v[r] = (v[r] + bb[j]) * oscale;
            if (mode == 1) {
                unsigned short* Cb = (unsigned short*)Cv;
                #pragma unroll
                for (int r = 0; r < 4; ++r) Cb[(size_t)(mb + r)*N + n] = f2bf(v[r]);
            } else if (mode == 3) {
                unsigned short* Cb = (unsigned short*)Cv;
                #pragma unroll
                for (int r = 0; r < 4; ++r) Cb[(size_t)(mb + r)*N + n] = f2bf(fmaxf(v[r], 0.f));
            } else if (mode == 4) {
                unsigned short* Cb = (unsigned short*)Cv;
                const int bI = mb / L, kk = mb % L;
                const int hh = n >> 5, d = n & 31;
                const int t2 = kk >> 5, dc = d >> 4, hi2 = (d >> 3) & 1;
                unsigned short* base = Cb
                    + ((size_t)(((bI*NH + hh)*(L >> 5) + t2)*2 + dc))*512
                    + ((kk & 31) + 32*hi2)*8 + (d & 7);
                base[0]  = f2bf(v[0]); base[8]  = f2bf(v[1]);
                base[16] = f2bf(v[2]); base[24] = f2bf(v[3]);
            } else {
                // mode 5: V fragment-major (contiguous ushort4)
                unsigned short* Cb = (unsigned short*)Cv;
                const int bI = mb / L, kk = mb % L;
                const int hh = n >> 5, d = n & 31;
                const int t = kk >> 6, oct = (kk >> 3) & 7;
                const int c = oct >> 1, hiV = oct & 1;
                ushort4 pk;
                pk.x = f2bf(v[0]); pk.y = f2bf(v[1]); pk.z = f2bf(v[2]); pk.w = f2bf(v[3]);
                *(ushort4*)(Cb
                    + ((size_t)(((bI*NH + hh)*(L >> 6) + t)*4 + c))*512
                    + (d + 32*hiV)*8 + (kk & 7)) = pk;
            }
        }
    }
}

// XCD-chunked swizzle over a 2D (nx,ny) grid slice; requires (nx*ny)%8==0.
static __device__ inline void xcd_swz(int d, int nx, int nxy, int& bx, int& by)
{
    const int w = (d & 7) * (nxy >> 3) + (d >> 3);
    bx = w % nx; by = w / nx;
}

__global__ __launch_bounds__(256) void gemm_mfma(const unsigned short* __restrict__ A,
    const unsigned short* __restrict__ W, const float* __restrict__ bias,
    void* __restrict__ C, int M, int N, int K, int mode, int L)
{
    int bx, by;
    xcd_swz(blockIdx.y*gridDim.x + blockIdx.x, gridDim.x, gridDim.x*gridDim.y, bx, by);
    gemm_core(A, W, bias, C, M, N, K, mode, L, 1.f, bx, by);
}

// fused Q/K/V projections: blockIdx.z selects which. Q pre-scaled by
// log2(e)/sqrt(32); K/V written fragment-major for register-direct attention.
__global__ __launch_bounds__(256) void qkv_mfma(const unsigned short* __restrict__ Aq,
    const unsigned short* __restrict__ Akv,
    const unsigned short* __restrict__ Wq, const float* __restrict__ bq,
    const unsigned short* __restrict__ Wk, const float* __restrict__ bk,
    const unsigned short* __restrict__ Wv, const float* __restrict__ bv,
    void* __restrict__ qo, void* __restrict__ ko, void* __restrict__ vo,
    int Mq, int Mkv, int L)
{
    const int z = blockIdx.z;
    const unsigned short* A = (z == 0) ? Aq : Akv;
    const unsigned short* W = (z == 0) ? Wq : ((z == 1) ? Wk : Wv);
    const float* bb = (z == 0) ? bq : ((z == 1) ? bk : bv);
    void* C = (z == 0) ? qo : ((z == 1) ? ko : vo);
    const int M = (z == 0) ? Mq : Mkv;
    const int mode = (z == 0) ? 1 : ((z == 1) ? 4 : 5);
    const float sc = (z == 0) ? 0.25504082364238727f : 1.f;   // log2(e)/sqrt(32)
    int bx, by;
    xcd_swz(blockIdx.y*gridDim.x + blockIdx.x, gridDim.x, gridDim.x*gridDim.y, bx, by);
    if (by * 128 >= M) return;
    gemm_core(A, W, bb, C, M, HID, HID, mode, L, sc, bx, by);
}

// ---------------- fused GEMM + residual + LayerNorm (N=256 full rows) -------
// 64-row x 256-col tile, 512 threads (8 waves), wave (wc2,wh) owns 32 cols.
// Staging identical to gemm_core (gload_lds + XOR swizzle). Epilogue stages
// acc+bias to LDS fp32 [64][260], then wave-per-row: +x residual, LN, write
// x fp32 + xb bf16; optional row norms (fuses norms_k for the final layer).
__global__ __launch_bounds__(512) void gemm_ln(const unsigned short* __restrict__ Ab,
    const unsigned short* __restrict__ Wb, const float* __restrict__ bias,
    const float* __restrict__ lng, const float* __restrict__ lnb,
    float* __restrict__ x, unsigned short* __restrict__ xb,
    float* __restrict__ nrm, int K)
{
    __shared__ __attribute__((aligned(16))) char smem[81920];
    unsigned short* As0 = (unsigned short*)smem;            // [2][64*64]   16KB
    unsigned short* Ws0 = (unsigned short*)(smem + 16384);  // [2][256*64]  64KB
    float* ys = (float*)smem;                               // [64][260] post-loop
    const int tid = threadIdx.x;
    const int w = tid >> 6, lane = tid & 63, lq = lane & 15, g = lane >> 4;
    const int wc2 = w & 3, wh = w >> 2;
    const int m0 = blockIdx.x * 64;

    const int srow = lane >> 3;
    const int scol = ((lane & 7) ^ srow) * 8;
    const int cswz = (lq & 7) * 8;

    f32x4 acc[4][2] = {};

    auto STAGE = [&](int kt, int buf) {
        const int k0 = kt * 64;
        {   const int row = w * 8;      // A: 8 chunks, one per wave
            gload16(Ab + (size_t)(m0 + row + srow)*K + k0 + scol,
                    As0 + buf*4096 + row*64);
        }
        #pragma unroll
        for (int c = 0; c < 4; ++c) {   // W: 32 chunks, 4 per wave
            const int row = w*32 + c*8;
            gload16(Wb + (size_t)(row + srow)*K + k0 + scol,
                    Ws0 + buf*16384 + row*64);
        }
    };

    const int nk = K / 64;
    STAGE(0, 0);
    __syncthreads();
    for (int kt = 0; kt < nk; ++kt) {
        const int cur = kt & 1;
        if (kt + 1 < nk) STAGE(kt + 1, cur ^ 1);
        const unsigned short* Ac = As0 + cur*4096;
        const unsigned short* Wc = Ws0 + cur*16384;
        #pragma unroll
        for (int ks = 0; ks < 2; ++ks) {
            const int co = (ks*32 + g*8) ^ cswz;
            bf16x8 bf0 = *(const bf16x8*)&Wc[(wc2*64 + wh*32 +  0 + lq)*64 + co];
            bf16x8 bf1 = *(const bf16x8*)&Wc[(wc2*64 + wh*32 + 16 + lq)*64 + co];
            #pragma unroll
            for (int i = 0; i < 4; ++i) {
                bf16x8 af = *(const bf16x8*)&Ac[(i*16 + lq)*64 + co];
                acc[i][0] = __builtin_amdgcn_mfma_f32_16x16x32_bf16(af, bf0, acc[i][0], 0, 0, 0);
                acc[i][1] = __builtin_amdgcn_mfma_f32_16x16x32_bf16(af, bf1, acc[i][1], 0, 0, 0);
            }
        }
        __syncthreads();   // also guards smem reuse below after last tile
    }

    float bb0 = bias[wc2*64 + wh*32 +  0 + lq];
    float bb1 = bias[wc2*64 + wh*32 + 16 + lq];
    #pragma unroll
    for (int i = 0; i < 4; ++i) {
        const int col0 = wc2*64 + wh*32 + lq;
        #pragma unroll
        for (int r = 0; r < 4; ++r) {
            const int row = i*16 + 4*g + r;
            ys[row*260 + col0]      = acc[i][0][r] + bb0;
            ys[row*260 + col0 + 16] = acc[i][1][r] + bb1;
        }
    }
    __syncthreads();

    // LN: wave w handles rows w*8 .. w*8+7
    float4 gv = *(const float4*)(lng + lane*4);
    float4 bv = *(const float4*)(lnb + lane*4);
    for (int it = 0; it < 8; ++it) {
        const int row = w*8 + it;
        const size_t gbase = (size_t)(m0 + row)*HID + lane*4;
        float4 y = *(float4*)&ys[row*260 + lane*4];
        float4 xv = *(const float4*)(x + gbase);
        y.x += xv.x; y.y += xv.y; y.z += xv.z; y.w += xv.w;
        float s = y.x + y.y + y.z + y.w;
        #pragma unroll
        for (int o = 32; o > 0; o >>= 1) s += __shfl_xor(s, o);
        float mean = s * (1.f/256.f);
        float4 d = {y.x - mean, y.y - mean, y.z - mean, y.w - mean};
        float q2 = d.x*d.x + d.y*d.y + d.z*d.z + d.w*d.w;
        #pragma unroll
        for (int o = 32; o > 0; o >>= 1) q2 += __shfl_xor(q2, o);
        float rs = rsqrtf(q2*(1.f/256.f) + 1e-5f);
        float4 ov;
        ov.x = d.x*rs*gv.x + bv.x; ov.y = d.y*rs*gv.y + bv.y;
        ov.z = d.z*rs*gv.z + bv.z; ov.w = d.w*rs*gv.w + bv.w;
        *(float4*)(x + gbase) = ov;
        ushort4 pk;
        pk.x = f2bf(ov.x); pk.y = f2bf(ov.y); pk.z = f2bf(ov.z); pk.w = f2bf(ov.w);
        *(ushort4*)(xb + gbase) = pk;
        if (nrm) {
            float q3 = ov.x*ov.x + ov.y*ov.y + ov.z*ov.z + ov.w*ov.w;
            #pragma unroll
            for (int o = 32; o > 0; o >>= 1) q3 += __shfl_xor(q3, o);
            if (lane == 0) nrm[m0 + row] = sqrtf(q3);
        }
    }
}

// ---------------- fused MFMA attention v6 ------------------------------------
// Register-dataflow flash attention: 32x32x16 MFMA, max-free softmax (Q
// pre-scaled), in-register P via cvt_pk + permlane32_swap. K/V come from
// fragment-major global layouts (KF/VF) so every operand load is ONE
// wave-contiguous 1KB global_load_dwordx4. No LDS staging, no barriers.
__global__ __launch_bounds__(256) void attn_mfma(const unsigned short* __restrict__ Qb,
    const unsigned short* __restrict__ KF, const unsigned short* __restrict__ VF,
    unsigned short* __restrict__ O, int Lk)
{
    __shared__ float Ll[4][32];
    const int orig = blockIdx.x;
    const int sw = (orig & 7) * 128 + (orig >> 3);   // XCD-chunk swizzle (1024%8==0)
    const int qt = sw & 3;
    const int h  = (sw >> 2) & 7;
    const int b  = sw >> 5;
    const int tid = threadIdx.x, w = tid >> 6, lane = tid & 63;
    const int q32 = lane & 31, hi = lane >> 5;

    // Q fragments (B-operand): lane -> (q=q32, d = dc*16 + hi*8 ..+7)
    const unsigned short* qp = Qb + ((size_t)(b*NA + qt*128 + w*32 + q32))*HID + h*DH + hi*8;
    bf16x8 qf0 = *(const bf16x8*)qp;
    bf16x8 qf1 = *(const bf16x8*)(qp + 16);

    const unsigned short* Kf = KF + (size_t)((b*NH + h)*(Lk >> 5)*2)*512 + lane*8;
    const unsigned short* Vf = VF + (size_t)((b*NH + h)*(Lk >> 6)*4)*512 + lane*8;

    f32x16 o_acc = ZERO16;
    float lacc = 0.f;

    bf16x8 kfA[4], kfB[4], vfT[4];
    auto LOADK = [&](int t, bf16x8* kd) {
        #pragma unroll
        for (int f = 0; f < 4; ++f)
            kd[f] = *(const bf16x8*)(Kf + (size_t)(t*4 + f)*512);
    };
    auto STEP = [&](const bf16x8* kf, int t) {
        #pragma unroll
        for (int c = 0; c < 4; ++c)
            vfT[c] = *(const bf16x8*)(Vf + (size_t)(t*4 + c)*512);
        f32x16 st0 = ZERO16, st1 = ZERO16;
        st0 = __builtin_amdgcn_mfma_f32_32x32x16_bf16(kf[0], qf0, st0, 0, 0, 0);
        st0 = __builtin_amdgcn_mfma_f32_32x32x16_bf16(kf[1], qf1, st0, 0, 0, 0);
        st1 = __builtin_amdgcn_mfma_f32_32x32x16_bf16(kf[2], qf0, st1, 0, 0, 0);
        st1 = __builtin_amdgcn_mfma_f32_32x32x16_bf16(kf[3], qf1, st1, 0, 0, 0);
        bf16x8 pa[4];
        float lp = 0.f;
        #pragma unroll
        for (int c = 0; c < 4; ++c) {
            const f32x16& s = (c < 2) ? st0 : st1;
            const int rb = (c & 1) * 8;
            float p0 = __builtin_amdgcn_exp2f(s[rb+0]);
            float p1 = __builtin_amdgcn_exp2f(s[rb+1]);
            float p2 = __builtin_amdgcn_exp2f(s[rb+2]);
            float p3 = __builtin_amdgcn_exp2f(s[rb+3]);
            float p4 = __builtin_amdgcn_exp2f(s[rb+4]);
            float p5 = __builtin_amdgcn_exp2f(s[rb+5]);
            float p6 = __builtin_amdgcn_exp2f(s[rb+6]);
            float p7 = __builtin_amdgcn_exp2f(s[rb+7]);
            lp += (p0+p1) + (p2+p3) + (p4+p5) + (p6+p7);
            unsigned A1 = cvtpk(p0, p1), A2 = cvtpk(p2, p3);
            unsigned B1 = cvtpk(p4, p5), B2 = cvtpk(p6, p7);
            auto r1 = __builtin_amdgcn_permlane32_swap(A1, B1, false, false);
            auto r2 = __builtin_amdgcn_permlane32_swap(A2, B2, false, false);
            u32x4 pw; pw[0] = r1[0]; pw[1] = r2[0]; pw[2] = r1[1]; pw[3] = r2[1];
            __builtin_memcpy(&pa[c], &pw, 16);
        }
        lacc += lp;
        #pragma unroll
        for (int c = 0; c < 4; ++c)
            o_acc = __builtin_amdgcn_mfma_f32_32x32x16_bf16(pa[c], vfT[c], o_acc, 0, 0, 0);
    };

    const int nt = Lk >> 6;   // 8 or 16 (even)
    LOADK(0, kfA);
    for (int t = 0; t < nt; t += 2) {
        LOADK(t + 1, kfB);
        STEP(kfA, t);
        if (t + 2 < nt) LOADK(t + 2, kfA);
        STEP(kfB, t + 1);
    }

    float lt = lacc + __shfl_xor(lacc, 32);
    float linv = 1.f / lt;
    if (hi == 0) Ll[w][q32] = linv;
    f32x4 li[4];
    #pragma unroll
    for (int jg = 0; jg < 4; ++jg) li[jg] = *(const f32x4*)&Ll[w][jg*8 + hi*4];

    unsigned short* Op = O + ((size_t)(b*NA + qt*128 + w*32))*HID + h*DH + q32;
    #pragma unroll
    for (int jg = 0; jg < 4; ++jg) {
        #pragma unroll
        for (int r2 = 0; r2 < 4; ++r2) {
            const int q = jg*8 + hi*4 + r2;
            Op[(size_t)q*HID] = f2bf(o_acc[jg*4 + r2] * li[jg][r2]);
        }
    }
}

// ---------------- pooling: softmax-weighted sum over rows -------------------
__global__ __launch_bounds__(256) void pooled_k(const float* __restrict__ x,
    const float* __restrict__ nw, float* __restrict__ pooled)
{
    __shared__ float sw[NA];
    __shared__ float red[256];
    __shared__ float part[8][33];
    const int b = blockIdx.x, hc = blockIdx.y;
    const int tid = threadIdx.x;
    const float* nb = nw + (size_t)b*NA;
    float v0 = nb[tid], v1 = nb[tid + 256];
    red[tid] = fmaxf(v0, v1); __syncthreads();
    for (int s = 128; s > 0; s >>= 1) { if (tid < s) red[tid] = fmaxf(red[tid], red[tid+s]); __syncthreads(); }
    float mx = red[0]; __syncthreads();
    float e0 = __expf(v0 - mx), e1 = __expf(v1 - mx);
    sw[tid] = e0; sw[tid + 256] = e1;
    red[tid] = e0 + e1; __syncthreads();
    for (int s = 128; s > 0; s >>= 1) { if (tid < s) red[tid] += red[tid+s]; __syncthreads(); }
    float inv = 1.f / red[0];
    __syncthreads();
    const int ng = tid >> 5, col = tid & 31;
    const float* xp = x + (size_t)b*NA*HID + hc*32 + col;
    float acc = 0.f;
    for (int n = ng; n < NA; n += 8)
        acc += sw[n] * xp[(size_t)n*HID];
    part[ng][col] = acc;
    __syncthreads();
    if (tid < 32) {
        float s = 0.f;
        #pragma unroll
        for (int i = 0; i < 8; ++i) s += part[i][tid];
        pooled[(size_t)b*HID + hc*32 + tid] = s * inv;
    }
}

// ---------------- FC head ---------------------------------------------------
__global__ __launch_bounds__(256) void head_k(const float* __restrict__ pooled,
    const float* __restrict__ fc1w, const float* __restrict__ fc1b,
    const float* __restrict__ fc2w, const float* __restrict__ fc2b,
    float* __restrict__ out)
{
    __shared__ float p[HID];
    __shared__ float a1[HID];
    const int b = blockIdx.x, tid = threadIdx.x;
    p[tid] = pooled[(size_t)b*HID + tid];
    __syncthreads();
    float s1 = fc1b[tid];
    const float* w1 = fc1w + (size_t)tid*HID;
    for (int k2 = 0; k2 < HID; k2 += 4) {
        float4 w = *(const float4*)(w1 + k2);
        s1 += p[k2]*w.x + p[k2+1]*w.y + p[k2+2]*w.z + p[k2+3]*w.w;
    }
    a1[tid] = fmaxf(s1, 0.f);
    __syncthreads();
    if (tid < 2) {
        float s2 = fc2b[tid];
        const float* w2 = fc2w + (size_t)tid*HID;
        for (int k2 = 0; k2 < HID; ++k2) s2 += a1[k2] * w2[k2];
        out[b*2 + tid] = s2;
    }
}

// ---------------- launch ----------------------------------------------------
extern "C" void kernel_launch(void* const* d_in, const int* in_sizes, int n_in,
                              void* d_out, int out_size, void* d_ws, size_t ws_size,
                              hipStream_t stream)
{
    const float* trg  = (const float*)d_in[0];
    const float* src  = (const float*)d_in[1];
    const float* ft_w = (const float*)d_in[2];
    const float* ft_b = (const float*)d_in[3];
    const float* ln_g = (const float*)d_in[4];
    const float* ln_b = (const float*)d_in[5];
    const float* sa_wq = (const float*)d_in[6];  const float* sa_bq = (const float*)d_in[7];
    const float* sa_wk = (const float*)d_in[8];  const float* sa_bk = (const float*)d_in[9];
    const float* sa_wv = (const float*)d_in[10]; const float* sa_bv = (const float*)d_in[11];
    const float* sa_wf = (const float*)d_in[12]; const float* sa_bf = (const float*)d_in[13];
    const float* ea_wq = (const float*)d_in[14]; const float* ea_bq = (const float*)d_in[15];
    const float* ea_wk = (const float*)d_in[16]; const float* ea_bk = (const float*)d_in[17];
    const float* ea_wv = (const float*)d_in[18]; const float* ea_bv = (const float*)d_in[19];
    const float* ea_wf = (const float*)d_in[20]; const float* ea_bf = (const float*)d_in[21];
    const float* pf_w1 = (const float*)d_in[22]; const float* pf_b1 = (const float*)d_in[23];
    const float* pf_w2 = (const float*)d_in[24]; const float* pf_b2 = (const float*)d_in[25];
    const float* fc1w  = (const float*)d_in[26]; const float* fc1b  = (const float*)d_in[27];
    const float* fc2w  = (const float*)d_in[28]; const float* fc2b  = (const float*)d_in[29];
    float* out = (float*)d_out;

    const size_t NTOK = (size_t)B_*NA;    // 16384
    const size_t NSRC = (size_t)B_*NP;    // 32768
    float* ws = (float*)d_ws;
    float* x  = ws;                        // [NTOK,HID] fp32 master
    float* nw = x + NTOK*HID;              // [NTOK] row norms
    float* pooled = nw + NTOK;             // [B_,HID]
    unsigned short* xb   = (unsigned short*)(pooled + B_*HID); // [NTOK,HID] bf16 shadow
    unsigned short* tb   = xb + NTOK*HID;                      // [NTOK,HID] bf16 attn-out
    unsigned short* srcb = tb + NTOK*HID;                      // [NSRC,HID] bf16
    unsigned short* qb   = srcb + NSRC*HID;                    // [NTOK,HID] bf16
    unsigned short* kb   = qb + NTOK*HID;                      // KF fragment-major bf16
    unsigned short* vTb  = kb + NSRC*HID;                      // VF fragment-major bf16
    unsigned short* wb   = vTb + NSRC*HID;                     // 2097152 bf16 weights
    unsigned short* hb   = qb;             // [NTOK,PF] bf16 aliases qb..vTb

    // pre-converted weight pointers
    unsigned short* saq_b = wb;
    unsigned short* sak_b = wb +  131072;
    unsigned short* sav_b = wb +  262144;
    unsigned short* saf_b = wb +  393216;
    unsigned short* eaq_b = wb +  524288;
    unsigned short* eak_b = wb +  655360;
    unsigned short* eav_b = wb +  786432;
    unsigned short* eaf_b = wb +  917504;
    unsigned short* pw1_b = wb + 1048576;
    unsigned short* pw2_b = wb + 1572864;

    const int M = (int)NTOK;
    dim3 blk(256);

    cvt_w<<<dim3(64, 1, 10), blk, 0, stream>>>(sa_wq, sa_wk, sa_wv, sa_wf,
        ea_wq, ea_wk, ea_wv, ea_wf, pf_w1, pf_w2, wb);
    ft_kernel<<<M/32, blk, 0, stream>>>(trg, ft_w, ft_b, x, xb);
    cvt_bf16<<<1024, blk, 0, stream>>>(src, srcb, (int)(NSRC*HID/8));

    for (int l = 0; l < 2; ++l) {
        const size_t wo = (size_t)l*HID*HID, bo = (size_t)l*HID;
        // ---- self attention ----
        qkv_mfma<<<dim3(HID/64, M/128, 3), blk, 0, stream>>>(xb, xb,
            saq_b+wo, sa_bq+bo, sak_b+wo, sa_bk+bo, sav_b+wo, sa_bv+bo,
            qb, kb, vTb, M, M, NA);
        attn_mfma<<<dim3(1024), blk, 0, stream>>>(qb, kb, vTb, tb, NA);
        gemm_ln<<<dim3(M/64), dim3(512), 0, stream>>>(tb, saf_b+wo, sa_bf+bo,
            ln_g+bo, ln_b+bo, x, xb, nullptr, HID);
        // ---- cross attention ----
        qkv_mfma<<<dim3(HID/64, (int)NSRC/128, 3), blk, 0, stream>>>(xb, srcb,
            eaq_b+wo, ea_bq+bo, eak_b+wo, ea_bk+bo, eav_b+wo, ea_bv+bo,
            qb, kb, vTb, M, (int)NSRC, NP);
        attn_mfma<<<dim3(1024), blk, 0, stream>>>(qb, kb, vTb, tb, NP);
        gemm_ln<<<dim3(M/64), dim3(512), 0, stream>>>(tb, eaf_b+wo, ea_bf+bo,
            ln_g+bo, ln_b+bo, x, xb, nullptr, HID);
        // ---- feed-forward ----
        gemm_mfma<<<dim3(PF/64, M/128), blk, 0, stream>>>(xb, pw1_b+(size_t)l*PF*HID, pf_b1+(size_t)l*PF, hb, M, PF, HID, 3, 0);
        gemm_ln<<<dim3(M/64), dim3(512), 0, stream>>>(hb, pw2_b+(size_t)l*HID*PF, pf_b2+bo,
            ln_g+bo, ln_b+bo, x, xb, (l == 1) ? nw : nullptr, PF);
    }

    pooled_k<<<dim3(B_, 8), blk, 0, stream>>>(x, nw, pooled);
    head_k<<<B_, blk, 0, stream>>>(pooled, fc1w, fc1b, fc2w, fc2b, out);
}